// Round 18
// baseline (308.378 us; speedup 1.0000x reference)
//
#include <hip/hip_runtime.h>
#include <hip/hip_bf16.h>
#include <math.h>

// ---------------- problem constants ----------------
#define T_TOK 2048
#define H_DIM 512
#define E_NUM 16
#define TOPK  2
#define I_DIM 2048
#define IS_DIM 1024
#define RPMAX 6144             // padded grouped rows (128-aligned per expert)
#define NRT128 (RPMAX / 128)   // 48
#define NRT64  (RPMAX / 64)    // 96

typedef __attribute__((ext_vector_type(8))) short bf16x8;
typedef __attribute__((ext_vector_type(4))) float f32x4;
typedef unsigned short ushort_t;

static __device__ __forceinline__ unsigned short f2bf(float f) {
  unsigned int u = __float_as_uint(f);
  unsigned int r = (u + 0x7fffu + ((u >> 16) & 1u)) >> 16;   // RNE
  return (unsigned short)r;
}

static __device__ __forceinline__ bf16x8 pack8(float4 a, float4 b) {
  bf16x8 v;
  v[0] = (short)f2bf(a.x); v[1] = (short)f2bf(a.y);
  v[2] = (short)f2bf(a.z); v[3] = (short)f2bf(a.w);
  v[4] = (short)f2bf(b.x); v[5] = (short)f2bf(b.y);
  v[6] = (short)f2bf(b.z); v[7] = (short)f2bf(b.w);
  return v;
}

// 2x float4 (8 consecutive fp32) -> one 16B bf16x8 unit via HW cvt_pk (RNE)
static __device__ __forceinline__ bf16x8 cvt8(float4 a, float4 b) {
  __hip_bfloat162 p0 = __float22bfloat162_rn(make_float2(a.x, a.y));
  __hip_bfloat162 p1 = __float22bfloat162_rn(make_float2(a.z, a.w));
  __hip_bfloat162 p2 = __float22bfloat162_rn(make_float2(b.x, b.y));
  __hip_bfloat162 p3 = __float22bfloat162_rn(make_float2(b.z, b.w));
  union { bf16x8 v; unsigned int u[4]; } r;
  r.u[0] = *(unsigned int*)&p0;
  r.u[1] = *(unsigned int*)&p1;
  r.u[2] = *(unsigned int*)&p2;
  r.u[3] = *(unsigned int*)&p3;
  return r.v;
}

// ================= fragment-major (FM) layout =================
// M[R][K] row-major -> chunk c = rg*(K/32) + kk; lane l holds
// M[rg*16 + (l&15)][kk*32 + (l>>4)*8 .. +8] (one bf16x8, 16B).

// ---------------- x fp32 -> FM bf16 with optional token gather ----------------
template <int LKC>
__global__ __launch_bounds__(256) void gatherA_kernel(const float* __restrict__ x,
                                                      const int* __restrict__ row_token,
                                                      ushort_t* __restrict__ d,
                                                      int n8, int K) {
  const int KC = 1 << LKC;
  int i = blockIdx.x * 256 + threadIdx.x;
  int stride = gridDim.x * 256;
  for (; i < n8; i += stride) {
    int l  = i & 63;
    int fi = i >> 6;
    int kk = fi & (KC - 1);
    int rg = fi >> LKC;
    int row = rg * 16 + (l & 15);
    int tok = row_token ? row_token[row] : row;
    bf16x8 v = {};
    if (tok >= 0) {
      const float* p = x + (size_t)tok * K + kk * 32 + (l >> 4) * 8;
      v = pack8(*(const float4*)p, *(const float4*)(p + 4));
    }
    ((bf16x8*)d)[i] = v;
  }
}

// ---------------- 1a) logits GEMV ----------------
__global__ __launch_bounds__(256) void logits_kernel(
    const float* __restrict__ x, const float* __restrict__ gw,
    float* __restrict__ logits)
{
  __shared__ float xs[16][516];
  int tid = threadIdx.x;
  int t0 = blockIdx.x * 16;
  for (int i = tid; i < 2048; i += 256) {
    int tt = i >> 7, q = i & 127;
    float4 v = ((const float4*)(x + (size_t)(t0 + tt) * H_DIM))[q];
    *(float4*)&xs[tt][q * 4] = v;
  }
  __syncthreads();
  int e = tid >> 4, tt = tid & 15;
  const float* gr = gw + (size_t)e * H_DIM;
  const float* xr = &xs[tt][0];
  int kbase = (blockIdx.x & 7) << 6;
  float acc = 0.f;
  #pragma unroll 8
  for (int kk = 0; kk < H_DIM; kk += 4) {
    int k = (kbase + kk) & (H_DIM - 1);
    float4 b = *(const float4*)(gr + k);
    float4 a = *(const float4*)(xr + k);
    acc += a.x * b.x + a.y * b.y + a.z * b.z + a.w * b.w;
  }
  logits[(size_t)(t0 + tt) * E_NUM + e] = acc;
}

// ---------------- 1b) softmax + top2 + histogram ----------------
__global__ __launch_bounds__(256) void topk_kernel(
    const float* __restrict__ logits,
    int* __restrict__ topk_idx, float* __restrict__ topk_w, int* __restrict__ counts)
{
  __shared__ int hist[E_NUM];
  int tid = threadIdx.x;
  if (tid < E_NUM) hist[tid] = 0;
  __syncthreads();
  int t = blockIdx.x * 256 + tid;
  float lg[E_NUM];
  #pragma unroll
  for (int i = 0; i < 4; i++) {
    float4 v = ((const float4*)(logits + (size_t)t * E_NUM))[i];
    lg[i * 4] = v.x; lg[i * 4 + 1] = v.y; lg[i * 4 + 2] = v.z; lg[i * 4 + 3] = v.w;
  }
  float mx = lg[0];
  #pragma unroll
  for (int i = 1; i < E_NUM; i++) mx = fmaxf(mx, lg[i]);
  float sc[E_NUM];
  float sum = 0.f;
  #pragma unroll
  for (int i = 0; i < E_NUM; i++) { sc[i] = expf(lg[i] - mx); sum += sc[i]; }
  float inv = 1.f / sum;
  float m1 = -1.f, m2 = -1.f; int i1 = 0, i2 = 0;
  #pragma unroll
  for (int i = 0; i < E_NUM; i++) {
    float s = sc[i] * inv;
    if (s > m1)      { m2 = m1; i2 = i1; m1 = s; i1 = i; }
    else if (s > m2) { m2 = s; i2 = i; }
  }
  topk_idx[t * 2] = i1; topk_idx[t * 2 + 1] = i2;
  topk_w[t * 2] = m1;  topk_w[t * 2 + 1] = m2;
  atomicAdd(&hist[i1], 1);
  atomicAdd(&hist[i2], 1);
  __syncthreads();
  if (tid < E_NUM) atomicAdd(&counts[tid], hist[tid]);
}

// ---------------- 2) 128-aligned padded scan + tile->expert maps ----------------
__global__ void offsets_kernel(const int* __restrict__ counts,
                               int* __restrict__ offp, int* __restrict__ cursor,
                               int* __restrict__ rt2e, int* __restrict__ rg2e)
{
  __shared__ int offs[E_NUM + 1];
  int tid = threadIdx.x;
  if (tid == 0) {
    int acc = 0;
    #pragma unroll
    for (int e = 0; e < E_NUM; e++) {
      offs[e] = acc; offp[e] = acc;
      acc += (counts[e] + 127) & ~127;
    }
    offs[E_NUM] = acc; offp[E_NUM] = acc;
  }
  if (tid < E_NUM) cursor[tid] = 0;
  __syncthreads();
  for (int r = tid; r < NRT128; r += 128) {
    int row = r << 7; int e = -1;
    #pragma unroll
    for (int i = 0; i < E_NUM; i++)
      if (row >= offs[i] && row < offs[i + 1]) e = i;
    rt2e[r] = e;
  }
  for (int r = tid; r < NRT64; r += 128) {
    int row = r << 6; int e = -1;
    #pragma unroll
    for (int i = 0; i < E_NUM; i++)
      if (row >= offs[i] && row < offs[i + 1]) e = i;
    rg2e[r] = e;
  }
}

// ---------------- 2b) init padded row arrays ----------------
__global__ __launch_bounds__(256) void initrows_kernel(int* __restrict__ row_token) {
  int i = blockIdx.x * 256 + threadIdx.x;
  if (i < RPMAX) row_token[i] = -1;
}

// ---------------- 3) scatter (+ inverse map trow) ----------------
__global__ __launch_bounds__(256) void scatter_kernel(
    const int* __restrict__ topk_idx, const float* __restrict__ topk_w,
    const int* __restrict__ offp, int* __restrict__ cursor,
    int* __restrict__ row_token, int* __restrict__ trow)
{
  int t = blockIdx.x * 256 + threadIdx.x;
  if (t >= T_TOK) return;
  #pragma unroll
  for (int k = 0; k < TOPK; k++) {
    int e = topk_idx[t * 2 + k];
    int pos = atomicAdd(&cursor[e], 1);
    int row = offp[e] + pos;
    row_token[row] = t;
    trow[t * 2 + k] = row;
  }
}

// ---------------- 4) GU GEMM: fused cvt, BK=64, 2-deep reg pipeline ----------
// Tile 128 rows x 64 cols, 4 waves (wm rows-64, wn cols-32), 8 phases of K=64.
// LDS/buf: A 16KB [0,16384), Bg 8KB [16384,24576), Bu 8KB [24576,32768).
// Two named register sets; loads issued TWO phases ahead of their ds_write.
__global__ __launch_bounds__(256, 2) void gu14_kernel(
    const ushort_t* __restrict__ xgf, const ushort_t* __restrict__ xsf,
    const float* __restrict__ wg_all, const float* __restrict__ wu_all,
    const float* __restrict__ swg, const float* __restrict__ swu,
    ushort_t* __restrict__ interF, ushort_t* __restrict__ interS,
    const int* __restrict__ rt2e)
{
  const int KC = H_DIM / 32;   // 16 chunks
  const int NP = KC / 2;       // 8 phases (even)
  int bid = blockIdx.x;
  int tid = threadIdx.x, w = tid >> 6, l = tid & 63;
  int wm = w >> 1, wn = w & 1;
  int fr = l & 15, g = l >> 4;

  const bf16x8* AF; const float *WG, *WU;
  bf16x8* OP;
  int rg0, c0, kkd0, KCd;

  if (bid < 32 * NRT128) {
    int cb = bid & 31, rt = bid >> 5;
    int e = rt2e[rt]; if (e < 0) return;
    rg0 = rt * 8;
    AF = (const bf16x8*)xgf;
    WG = wg_all + (size_t)e * I_DIM * H_DIM;
    WU = wu_all + (size_t)e * I_DIM * H_DIM;
    c0 = cb * 64;
    KCd = I_DIM >> 5; kkd0 = cb * 2 + wn;
    OP = (bf16x8*)interF;
  } else {
    int b2 = bid - 32 * NRT128;
    int cb = b2 & 15, rt = b2 >> 4;
    rg0 = rt * 8;
    AF = (const bf16x8*)xsf;
    WG = swg; WU = swu;
    c0 = cb * 64;
    KCd = IS_DIM >> 5; kkd0 = cb * 2 + wn;
    OP = (bf16x8*)interS;
  }

  __shared__ ushort_t sm[2][16384];   // 64 KB

  // A staging: 1024 units (16 chunks: ca = rga*2+kc), 4 per thread
  const bf16x8* abase[4]; int auo[4];
  #pragma unroll
  for (int j = 0; j < 4; j++) {
    int u = tid + j * 256;
    auo[j] = u;
    int ca = u >> 6, la = u & 63;
    abase[j] = AF + ((size_t)(rg0 + (ca >> 1)) * KC + (ca & 1)) * 64 + la;
  }
  // B staging: 512 units/op (8 chunks), 2 per thread per op
  const float* bsrc[2]; int buo[2];
  #pragma unroll
  for (int i = 0; i < 2; i++) {
    int u = tid + i * 256;
    buo[i] = u;
    int cb2 = u >> 6, lb = u & 63;
    int row = c0 + (cb2 >> 1) * 16 + (lb & 15);
    bsrc[i] = WG + (size_t)row * H_DIM + (cb2 & 1) * 32 + (lb >> 4) * 8;
  }
  ptrdiff_t dWU = WU - WG;

  f32x4 accg[4][2] = {}, accu[4][2] = {};
  // register set A (even phases)
  bf16x8 raA[4]; float4 gA[2][2], uA[2][2];
  // register set B (odd phases)
  bf16x8 raB[4]; float4 gB[2][2], uB[2][2];

  auto loadS0 = [&](int p) {
    #pragma unroll
    for (int j = 0; j < 4; j++) raA[j] = abase[j][(size_t)(2 * p) * 64];
    #pragma unroll
    for (int i = 0; i < 2; i++) {
      const float* pg = bsrc[i] + p * 64;
      gA[i][0] = *(const float4*)pg;
      gA[i][1] = *(const float4*)(pg + 4);
      uA[i][0] = *(const float4*)(pg + dWU);
      uA[i][1] = *(const float4*)(pg + dWU + 4);
    }
  };
  auto loadS1 = [&](int p) {
    #pragma unroll
    for (int j = 0; j < 4; j++) raB[j] = abase[j][(size_t)(2 * p) * 64];
    #pragma unroll
    for (int i = 0; i < 2; i++) {
      const float* pg = bsrc[i] + p * 64;
      gB[i][0] = *(const float4*)pg;
      gB[i][1] = *(const float4*)(pg + 4);
      uB[i][0] = *(const float4*)(pg + dWU);
      uB[i][1] = *(const float4*)(pg + dWU + 4);
    }
  };
  auto storeS0 = [&](int b) {
    char* pb = (char*)sm[b];
    #pragma unroll
    for (int j = 0; j < 4; j++)
      *(bf16x8*)(pb + auo[j] * 16) = raA[j];
    #pragma unroll
    for (int i = 0; i < 2; i++) {
      *(bf16x8*)(pb + 16384 + buo[i] * 16) = cvt8(gA[i][0], gA[i][1]);
      *(bf16x8*)(pb + 24576 + buo[i] * 16) = cvt8(uA[i][0], uA[i][1]);
    }
  };
  auto storeS1 = [&](int b) {
    char* pb = (char*)sm[b];
    #pragma unroll
    for (int j = 0; j < 4; j++)
      *(bf16x8*)(pb + auo[j] * 16) = raB[j];
    #pragma unroll
    for (int i = 0; i < 2; i++) {
      *(bf16x8*)(pb + 16384 + buo[i] * 16) = cvt8(gB[i][0], gB[i][1]);
      *(bf16x8*)(pb + 24576 + buo[i] * 16) = cvt8(uB[i][0], uB[i][1]);
    }
  };
  auto compute = [&](int b) {
    char* pb = (char*)sm[b];
    __builtin_amdgcn_s_setprio(1);
    #pragma unroll
    for (int s = 0; s < 2; s++) {
      bf16x8 af[4], bg[2], bu[2];
      #pragma unroll
      for (int mi = 0; mi < 4; mi++)
        af[mi] = *(const bf16x8*)(pb + ((wm * 4 + mi) * 2 + s) * 1024 + l * 16);
      #pragma unroll
      for (int ni = 0; ni < 2; ni++) {
        bg[ni] = *(const bf16x8*)(pb + 16384 + ((wn * 2 + ni) * 2 + s) * 1024 + l * 16);
        bu[ni] = *(const bf16x8*)(pb + 24576 + ((wn * 2 + ni) * 2 + s) * 1024 + l * 16);
      }
      #pragma unroll
      for (int mi = 0; mi < 4; mi++)
        #pragma unroll
        for (int ni = 0; ni < 2; ni++) {
          accg[mi][ni] = __builtin_amdgcn_mfma_f32_16x16x32_bf16(af[mi], bg[ni], accg[mi][ni], 0, 0, 0);
          accu[mi][ni] = __builtin_amdgcn_mfma_f32_16x16x32_bf16(af[mi], bu[ni], accu[mi][ni], 0, 0, 0);
        }
    }
    __builtin_amdgcn_s_setprio(0);
  };

  loadS0(0); loadS1(1);
  storeS0(0);
  asm volatile("s_waitcnt lgkmcnt(0)" ::: "memory");
  __builtin_amdgcn_s_barrier();
  for (int p = 0; p < NP; p += 2) {
    if (p + 2 < NP) loadS0(p + 2);
    compute(0);
    storeS1(1);
    asm volatile("s_waitcnt lgkmcnt(0)" ::: "memory");
    __builtin_amdgcn_s_barrier();
    if (p + 3 < NP) loadS1(p + 3);
    compute(1);
    if (p + 2 < NP) storeS0(0);
    asm volatile("s_waitcnt lgkmcnt(0)" ::: "memory");
    __builtin_amdgcn_s_barrier();
  }

  // epilogue: silu(g)*u -> per-wave bounce (64x32, stride 40) -> FM write
  ushort_t* bw = &sm[0][0] + w * (64 * 40);
  #pragma unroll
  for (int mi = 0; mi < 4; mi++)
    #pragma unroll
    for (int ni = 0; ni < 2; ni++)
      #pragma unroll
      for (int j = 0; j < 4; j++) {
        float gg = accg[mi][ni][j], uu = accu[mi][ni][j];
        float s = (gg / (1.f + expf(-gg))) * uu;
        bw[(mi * 16 + g * 4 + j) * 40 + ni * 16 + fr] = f2bf(s);
      }
  #pragma unroll
  for (int rgi = 0; rgi < 4; rgi++) {
    bf16x8 v = *(const bf16x8*)&bw[(rgi * 16 + (l & 15)) * 40 + (l >> 4) * 8];
    OP[((size_t)(rg0 + wm * 4 + rgi) * KCd + kkd0) * 64 + l] = v;
  }
}

// ---------------- 5) down GEMM: fused cvt, BK=64, 2-deep reg pipeline --------
// Tile 64 rows x 128 cols, 4 waves (each 64 rows x 32 cols), phases of K=64.
// LDS/buf: A 8KB [0,8192), B 16KB [8192,24576).
__global__ __launch_bounds__(256, 3) void down14_kernel(
    const ushort_t* __restrict__ interF, const ushort_t* __restrict__ interS,
    const float* __restrict__ wd_all, const float* __restrict__ swd,
    float* __restrict__ Dr, float* __restrict__ Ds,
    const int* __restrict__ rg2e)
{
  int bid = blockIdx.x;
  int tid = threadIdx.x, w = tid >> 6, l = tid & 63;
  int fr = l & 15, g = l >> 4;

  const bf16x8* AF; const float* WD;
  float* DO;
  int rgA0, c0, NP, KCa, row0;

  if (bid < 4 * NRT64) {
    int cb = bid & 3, rt = bid >> 2;
    int e = rg2e[rt]; if (e < 0) return;
    AF = (const bf16x8*)interF;
    WD = wd_all + (size_t)e * H_DIM * I_DIM;
    rgA0 = rt * 4; c0 = cb * 128;
    KCa = I_DIM >> 5; NP = I_DIM >> 6;   // 32 phases (even)
    row0 = rt * 64;
    DO = Dr;
  } else {
    int b2 = bid - 4 * NRT64;
    int cb = b2 & 3, rt = b2 >> 2;
    AF = (const bf16x8*)interS;
    WD = swd;
    rgA0 = rt * 4; c0 = cb * 128;
    KCa = IS_DIM >> 5; NP = IS_DIM >> 6; // 16 phases (even)
    row0 = rt * 64;
    DO = Ds;
  }
  int Kd = KCa * 32;   // row length in floats

  __shared__ ushort_t sm[2][12288];   // 48 KB

  // A staging: 512 units (8 chunks: ca = rga*2+kc), 2 per thread
  const bf16x8* abase[2]; int auo[2];
  #pragma unroll
  for (int j = 0; j < 2; j++) {
    int u = tid + j * 256;
    auo[j] = u;
    int ca = u >> 6, la = u & 63;
    abase[j] = AF + ((size_t)(rgA0 + (ca >> 1)) * KCa + (ca & 1)) * 64 + la;
  }
  // B staging: 1024 units (16 chunks), 4 per thread
  const float* bsrc[4]; int buo[4];
  #pragma unroll
  for (int i = 0; i < 4; i++) {
    int u = tid + i * 256;
    buo[i] = u;
    int cb2 = u >> 6, lb = u & 63;
    int row = c0 + (cb2 >> 1) * 16 + (lb & 15);
    bsrc[i] = WD + (size_t)row * Kd + (cb2 & 1) * 32 + (lb >> 4) * 8;
  }

  f32x4 acc[4][2] = {};
  bf16x8 raA[2]; float4 bA[4][2];
  bf16x8 raB[2]; float4 bB[4][2];

  auto loadS0 = [&](int p) {
    #pragma unroll
    for (int j = 0; j < 2; j++) raA[j] = abase[j][(size_t)(2 * p) * 64];
    #pragma unroll
    for (int i = 0; i < 4; i++) {
      const float* pg = bsrc[i] + p * 64;
      bA[i][0] = *(const float4*)pg;
      bA[i][1] = *(const float4*)(pg + 4);
    }
  };
  auto loadS1 = [&](int p) {
    #pragma unroll
    for (int j = 0; j < 2; j++) raB[j] = abase[j][(size_t)(2 * p) * 64];
    #pragma unroll
    for (int i = 0; i < 4; i++) {
      const float* pg = bsrc[i] + p * 64;
      bB[i][0] = *(const float4*)pg;
      bB[i][1] = *(const float4*)(pg + 4);
    }
  };
  auto storeS0 = [&](int b) {
    char* pb = (char*)sm[b];
    #pragma unroll
    for (int j = 0; j < 2; j++)
      *(bf16x8*)(pb + auo[j] * 16) = raA[j];
    #pragma unroll
    for (int i = 0; i < 4; i++)
      *(bf16x8*)(pb + 8192 + buo[i] * 16) = cvt8(bA[i][0], bA[i][1]);
  };
  auto storeS1 = [&](int b) {
    char* pb = (char*)sm[b];
    #pragma unroll
    for (int j = 0; j < 2; j++)
      *(bf16x8*)(pb + auo[j] * 16) = raB[j];
    #pragma unroll
    for (int i = 0; i < 4; i++)
      *(bf16x8*)(pb + 8192 + buo[i] * 16) = cvt8(bB[i][0], bB[i][1]);
  };
  auto compute = [&](int b) {
    char* pb = (char*)sm[b];
    __builtin_amdgcn_s_setprio(1);
    #pragma unroll
    for (int s = 0; s < 2; s++) {
      bf16x8 af[4], bf[2];
      #pragma unroll
      for (int mi = 0; mi < 4; mi++)
        af[mi] = *(const bf16x8*)(pb + (mi * 2 + s) * 1024 + l * 16);
      #pragma unroll
      for (int ni = 0; ni < 2; ni++)
        bf[ni] = *(const bf16x8*)(pb + 8192 + ((w * 2 + ni) * 2 + s) * 1024 + l * 16);
      #pragma unroll
      for (int mi = 0; mi < 4; mi++)
        #pragma unroll
        for (int ni = 0; ni < 2; ni++)
          acc[mi][ni] = __builtin_amdgcn_mfma_f32_16x16x32_bf16(af[mi], bf[ni], acc[mi][ni], 0, 0, 0);
    }
    __builtin_amdgcn_s_setprio(0);
  };

  loadS0(0); loadS1(1);
  storeS0(0);
  asm volatile("s_waitcnt lgkmcnt(0)" ::: "memory");
  __builtin_amdgcn_s_barrier();
  for (int p = 0; p < NP; p += 2) {
    if (p + 2 < NP) loadS0(p + 2);
    compute(0);
    storeS1(1);
    asm volatile("s_waitcnt lgkmcnt(0)" ::: "memory");
    __builtin_amdgcn_s_barrier();
    if (p + 3 < NP) loadS1(p + 3);
    compute(1);
    if (p + 2 < NP) storeS0(0);
    asm volatile("s_waitcnt lgkmcnt(0)" ::: "memory");
    __builtin_amdgcn_s_barrier();
  }

  #pragma unroll
  for (int mi = 0; mi < 4; mi++)
    #pragma unroll
    for (int ni = 0; ni < 2; ni++)
      #pragma unroll
      for (int j = 0; j < 4; j++)
        DO[(size_t)(row0 + mi * 16 + g * 4 + j) * H_DIM + c0 + w * 32 + ni * 16 + fr]
            = acc[mi][ni][j];
}

// ---------------- 6) combine: out[t] = w0*Dr[r0] + w1*Dr[r1] + Ds[t] ----------
__global__ __launch_bounds__(128) void combine_kernel(
    const float* __restrict__ Dr, const float* __restrict__ Ds,
    const int* __restrict__ trow, const float* __restrict__ topk_w,
    float* __restrict__ out)
{
  int t = blockIdx.x, c = threadIdx.x;
  int r0 = trow[t * 2], r1 = trow[t * 2 + 1];
  float w0 = topk_w[t * 2], w1 = topk_w[t * 2 + 1];
  float4 a = ((const float4*)(Dr + (size_t)r0 * H_DIM))[c];
  float4 b = ((const float4*)(Dr + (size_t)r1 * H_DIM))[c];
  float4 s = ((const float4*)(Ds + (size_t)t * H_DIM))[c];
  float4 r;
  r.x = w0 * a.x + w1 * b.x + s.x;
  r.y = w0 * a.y + w1 * b.y + s.y;
  r.z = w0 * a.z + w1 * b.z + s.z;
  r.w = w0 * a.w + w1 * b.w + s.w;
  ((float4*)(out + (size_t)t * H_DIM))[c] = r;
}

// ---------------- launch ----------------
extern "C" void kernel_launch(void* const* d_in, const int* in_sizes, int n_in,
                              void* d_out, int out_size, void* d_ws, size_t ws_size,
                              hipStream_t stream) {
  const float* x       = (const float*)d_in[0];
  const float* gate_w  = (const float*)d_in[1];
  const float* w_gate  = (const float*)d_in[2];
  const float* w_up    = (const float*)d_in[3];
  const float* w_down  = (const float*)d_in[4];
  const float* sw_gate = (const float*)d_in[5];
  const float* sw_up   = (const float*)d_in[6];
  const float* sw_down = (const float*)d_in[7];
  float* out = (float*)d_out;

  char* ws = (char*)d_ws;
  int*   counts    = (int*)ws;                      // 16
  int*   cursor    = (int*)(ws + 64);               // 16
  int*   offp      = (int*)(ws + 128);              // 17
  int*   rt2e      = (int*)(ws + 256);              // 48
  int*   rg2e      = (int*)(ws + 448);              // 96
  int*   topk_idx  = (int*)(ws + 832);              // 4096
  float* topk_w    = (float*)(ws + 17216);          // 4096
  int*   trow      = (int*)(ws + 33600);            // 4096
  int*   row_token = (int*)(ws + 49984);            // RPMAX
  size_t off = 49984 + (size_t)RPMAX * 4;
  off = (off + 255) & ~(size_t)255;
  float*    logits = (float*)(ws + off);    off += (size_t)T_TOK * E_NUM * 4;       // 128 KiB
  ushort_t* xgf  = (ushort_t*)(ws + off); off += (size_t)RPMAX * H_DIM * 2;         // 6 MiB
  ushort_t* xsf  = (ushort_t*)(ws + off); off += (size_t)T_TOK * H_DIM * 2;         // 2 MiB
  ushort_t* interF = (ushort_t*)(ws + off); off += (size_t)RPMAX * I_DIM * 2;       // 24 MiB
  ushort_t* interS = (ushort_t*)(ws + off); off += (size_t)T_TOK * IS_DIM * 2;      // 4 MiB
  float*    Dr     = (float*)(ws + off);    off += (size_t)RPMAX * H_DIM * 4;       // 12 MiB
  float*    Ds     = (float*)(ws + off);    off += (size_t)T_TOK * H_DIM * 4;       // 4 MiB

  hipMemsetAsync(counts, 0, 64, stream);
  logits_kernel<<<T_TOK / 16, 256, 0, stream>>>(x, gate_w, logits);
  topk_kernel<<<T_TOK / 256, 256, 0, stream>>>(logits, topk_idx, topk_w, counts);
  offsets_kernel<<<1, 128, 0, stream>>>(counts, offp, cursor, rt2e, rg2e);
  initrows_kernel<<<RPMAX / 256, 256, 0, stream>>>(row_token);
  scatter_kernel<<<(T_TOK + 255) / 256, 256, 0, stream>>>(topk_idx, topk_w, offp, cursor,
                                                          row_token, trow);
  // A-operands into FM bf16
  gatherA_kernel<4><<<RPMAX * H_DIM / 8 / 256, 256, 0, stream>>>(
      x, row_token, xgf, RPMAX * H_DIM / 8, H_DIM);
  gatherA_kernel<4><<<T_TOK * H_DIM / 8 / 256, 256, 0, stream>>>(
      x, nullptr, xsf, T_TOK * H_DIM / 8, H_DIM);

  // GU (fused conversion): routed 32 cb x 48 rt = 1536 + shared 16 x 16 = 256
  gu14_kernel<<<32 * NRT128 + 16 * 16, 256, 0, stream>>>(
      xgf, xsf, w_gate, w_up, sw_gate, sw_up, interF, interS, rt2e);
  // down (fused conversion): routed 4 cb x 96 rt = 384 + shared 4 x 32 = 128
  down14_kernel<<<4 * NRT64 + 4 * 32, 256, 0, stream>>>(
      interF, interS, w_down, sw_down, Dr, Ds, rg2e);
  // combine
  combine_kernel<<<T_TOK, 128, 0, stream>>>(Dr, Ds, trow, topk_w, out);
}

// Round 19
// 236.745 us; speedup vs baseline: 1.3026x; 1.3026x over previous
//
#include <hip/hip_runtime.h>
#include <hip/hip_bf16.h>
#include <math.h>

// ---------------- problem constants ----------------
#define T_TOK 2048
#define H_DIM 512
#define E_NUM 16
#define TOPK  2
#define I_DIM 2048
#define IS_DIM 1024
#define RPMAX 6144             // padded grouped rows (128-aligned per expert)
#define NRT128 (RPMAX / 128)   // 48
#define NRT64  (RPMAX / 64)    // 96

typedef __attribute__((ext_vector_type(8))) short bf16x8;
typedef __attribute__((ext_vector_type(4))) float f32x4;
typedef unsigned short ushort_t;

static __device__ __forceinline__ unsigned short f2bf(float f) {
  unsigned int u = __float_as_uint(f);
  unsigned int r = (u + 0x7fffu + ((u >> 16) & 1u)) >> 16;   // RNE
  return (unsigned short)r;
}

static __device__ __forceinline__ bf16x8 pack8(float4 a, float4 b) {
  bf16x8 v;
  v[0] = (short)f2bf(a.x); v[1] = (short)f2bf(a.y);
  v[2] = (short)f2bf(a.z); v[3] = (short)f2bf(a.w);
  v[4] = (short)f2bf(b.x); v[5] = (short)f2bf(b.y);
  v[6] = (short)f2bf(b.z); v[7] = (short)f2bf(b.w);
  return v;
}

// 2x float4 (8 consecutive fp32) -> one 16B bf16x8 unit via HW cvt_pk (RNE)
static __device__ __forceinline__ bf16x8 cvt8(float4 a, float4 b) {
  __hip_bfloat162 p0 = __float22bfloat162_rn(make_float2(a.x, a.y));
  __hip_bfloat162 p1 = __float22bfloat162_rn(make_float2(a.z, a.w));
  __hip_bfloat162 p2 = __float22bfloat162_rn(make_float2(b.x, b.y));
  __hip_bfloat162 p3 = __float22bfloat162_rn(make_float2(b.z, b.w));
  union { bf16x8 v; unsigned int u[4]; } r;
  r.u[0] = *(unsigned int*)&p0;
  r.u[1] = *(unsigned int*)&p1;
  r.u[2] = *(unsigned int*)&p2;
  r.u[3] = *(unsigned int*)&p3;
  return r.v;
}

// ================= fragment-major (FM) layout =================
// M[R][K] row-major -> chunk c = rg*(K/32) + kk; lane l holds
// M[rg*16 + (l&15)][kk*32 + (l>>4)*8 .. +8] (one bf16x8, 16B).

// ---------------- x fp32 -> FM bf16 with optional token gather ----------------
template <int LKC>
__global__ __launch_bounds__(256) void gatherA_kernel(const float* __restrict__ x,
                                                      const int* __restrict__ row_token,
                                                      ushort_t* __restrict__ d,
                                                      int n8, int K) {
  const int KC = 1 << LKC;
  int i = blockIdx.x * 256 + threadIdx.x;
  int stride = gridDim.x * 256;
  for (; i < n8; i += stride) {
    int l  = i & 63;
    int fi = i >> 6;
    int kk = fi & (KC - 1);
    int rg = fi >> LKC;
    int row = rg * 16 + (l & 15);
    int tok = row_token ? row_token[row] : row;
    bf16x8 v = {};
    if (tok >= 0) {
      const float* p = x + (size_t)tok * K + kk * 32 + (l >> 4) * 8;
      v = pack8(*(const float4*)p, *(const float4*)(p + 4));
    }
    ((bf16x8*)d)[i] = v;
  }
}

// ---------------- 1a) logits GEMV ----------------
__global__ __launch_bounds__(256) void logits_kernel(
    const float* __restrict__ x, const float* __restrict__ gw,
    float* __restrict__ logits)
{
  __shared__ float xs[16][516];
  int tid = threadIdx.x;
  int t0 = blockIdx.x * 16;
  for (int i = tid; i < 2048; i += 256) {
    int tt = i >> 7, q = i & 127;
    float4 v = ((const float4*)(x + (size_t)(t0 + tt) * H_DIM))[q];
    *(float4*)&xs[tt][q * 4] = v;
  }
  __syncthreads();
  int e = tid >> 4, tt = tid & 15;
  const float* gr = gw + (size_t)e * H_DIM;
  const float* xr = &xs[tt][0];
  int kbase = (blockIdx.x & 7) << 6;
  float acc = 0.f;
  #pragma unroll 8
  for (int kk = 0; kk < H_DIM; kk += 4) {
    int k = (kbase + kk) & (H_DIM - 1);
    float4 b = *(const float4*)(gr + k);
    float4 a = *(const float4*)(xr + k);
    acc += a.x * b.x + a.y * b.y + a.z * b.z + a.w * b.w;
  }
  logits[(size_t)(t0 + tt) * E_NUM + e] = acc;
}

// ---------------- 1b) softmax + top2 + histogram ----------------
__global__ __launch_bounds__(256) void topk_kernel(
    const float* __restrict__ logits,
    int* __restrict__ topk_idx, float* __restrict__ topk_w, int* __restrict__ counts)
{
  __shared__ int hist[E_NUM];
  int tid = threadIdx.x;
  if (tid < E_NUM) hist[tid] = 0;
  __syncthreads();
  int t = blockIdx.x * 256 + tid;
  float lg[E_NUM];
  #pragma unroll
  for (int i = 0; i < 4; i++) {
    float4 v = ((const float4*)(logits + (size_t)t * E_NUM))[i];
    lg[i * 4] = v.x; lg[i * 4 + 1] = v.y; lg[i * 4 + 2] = v.z; lg[i * 4 + 3] = v.w;
  }
  float mx = lg[0];
  #pragma unroll
  for (int i = 1; i < E_NUM; i++) mx = fmaxf(mx, lg[i]);
  float sc[E_NUM];
  float sum = 0.f;
  #pragma unroll
  for (int i = 0; i < E_NUM; i++) { sc[i] = expf(lg[i] - mx); sum += sc[i]; }
  float inv = 1.f / sum;
  float m1 = -1.f, m2 = -1.f; int i1 = 0, i2 = 0;
  #pragma unroll
  for (int i = 0; i < E_NUM; i++) {
    float s = sc[i] * inv;
    if (s > m1)      { m2 = m1; i2 = i1; m1 = s; i1 = i; }
    else if (s > m2) { m2 = s; i2 = i; }
  }
  topk_idx[t * 2] = i1; topk_idx[t * 2 + 1] = i2;
  topk_w[t * 2] = m1;  topk_w[t * 2 + 1] = m2;
  atomicAdd(&hist[i1], 1);
  atomicAdd(&hist[i2], 1);
  __syncthreads();
  if (tid < E_NUM) atomicAdd(&counts[tid], hist[tid]);
}

// ---------------- 2) 128-aligned padded scan + tile->expert maps ----------------
__global__ void offsets_kernel(const int* __restrict__ counts,
                               int* __restrict__ offp, int* __restrict__ cursor,
                               int* __restrict__ rt2e, int* __restrict__ rg2e)
{
  __shared__ int offs[E_NUM + 1];
  int tid = threadIdx.x;
  if (tid == 0) {
    int acc = 0;
    #pragma unroll
    for (int e = 0; e < E_NUM; e++) {
      offs[e] = acc; offp[e] = acc;
      acc += (counts[e] + 127) & ~127;
    }
    offs[E_NUM] = acc; offp[E_NUM] = acc;
  }
  if (tid < E_NUM) cursor[tid] = 0;
  __syncthreads();
  for (int r = tid; r < NRT128; r += 128) {
    int row = r << 7; int e = -1;
    #pragma unroll
    for (int i = 0; i < E_NUM; i++)
      if (row >= offs[i] && row < offs[i + 1]) e = i;
    rt2e[r] = e;
  }
  for (int r = tid; r < NRT64; r += 128) {
    int row = r << 6; int e = -1;
    #pragma unroll
    for (int i = 0; i < E_NUM; i++)
      if (row >= offs[i] && row < offs[i + 1]) e = i;
    rg2e[r] = e;
  }
}

// ---------------- 2b) init padded row arrays ----------------
__global__ __launch_bounds__(256) void initrows_kernel(int* __restrict__ row_token) {
  int i = blockIdx.x * 256 + threadIdx.x;
  if (i < RPMAX) row_token[i] = -1;
}

// ---------------- 3) scatter (+ inverse map trow) ----------------
__global__ __launch_bounds__(256) void scatter_kernel(
    const int* __restrict__ topk_idx, const float* __restrict__ topk_w,
    const int* __restrict__ offp, int* __restrict__ cursor,
    int* __restrict__ row_token, int* __restrict__ trow)
{
  int t = blockIdx.x * 256 + threadIdx.x;
  if (t >= T_TOK) return;
  #pragma unroll
  for (int k = 0; k < TOPK; k++) {
    int e = topk_idx[t * 2 + k];
    int pos = atomicAdd(&cursor[e], 1);
    int row = offp[e] + pos;
    row_token[row] = t;
    trow[t * 2 + k] = row;
  }
}

// ---------------- 4) GU GEMM: fused cvt, BK=64, 2-deep reg pipeline ----------
// Tile 128 rows x 64 cols, 4 waves (wm rows-64, wn cols-32), 8 phases of K=64.
// LDS/buf: A 16KB [0,16384), Bg 8KB [16384,24576), Bu 8KB [24576,32768).
// Two named register sets; loads issued TWO phases ahead of their ds_write.
__global__ __launch_bounds__(256, 2) void gu14_kernel(
    const ushort_t* __restrict__ xgf, const ushort_t* __restrict__ xsf,
    const float* __restrict__ wg_all, const float* __restrict__ wu_all,
    const float* __restrict__ swg, const float* __restrict__ swu,
    ushort_t* __restrict__ interF, ushort_t* __restrict__ interS,
    const int* __restrict__ rt2e)
{
  const int KC = H_DIM / 32;   // 16 chunks
  const int NP = KC / 2;       // 8 phases (even)
  int bid = blockIdx.x;
  int tid = threadIdx.x, w = tid >> 6, l = tid & 63;
  int wm = w >> 1, wn = w & 1;
  int fr = l & 15, g = l >> 4;

  const bf16x8* AF; const float *WG, *WU;
  bf16x8* OP;
  int rg0, c0, kkd0, KCd;

  if (bid < 32 * NRT128) {
    int cb = bid & 31, rt = bid >> 5;
    int e = rt2e[rt]; if (e < 0) return;
    rg0 = rt * 8;
    AF = (const bf16x8*)xgf;
    WG = wg_all + (size_t)e * I_DIM * H_DIM;
    WU = wu_all + (size_t)e * I_DIM * H_DIM;
    c0 = cb * 64;
    KCd = I_DIM >> 5; kkd0 = cb * 2 + wn;
    OP = (bf16x8*)interF;
  } else {
    int b2 = bid - 32 * NRT128;
    int cb = b2 & 15, rt = b2 >> 4;
    rg0 = rt * 8;
    AF = (const bf16x8*)xsf;
    WG = swg; WU = swu;
    c0 = cb * 64;
    KCd = IS_DIM >> 5; kkd0 = cb * 2 + wn;
    OP = (bf16x8*)interS;
  }

  __shared__ ushort_t sm[2][16384];   // 64 KB

  // A staging: 1024 units (16 chunks: ca = rga*2+kc), 4 per thread
  const bf16x8* abase[4]; int auo[4];
  #pragma unroll
  for (int j = 0; j < 4; j++) {
    int u = tid + j * 256;
    auo[j] = u;
    int ca = u >> 6, la = u & 63;
    abase[j] = AF + ((size_t)(rg0 + (ca >> 1)) * KC + (ca & 1)) * 64 + la;
  }
  // B staging: 512 units/op (8 chunks), 2 per thread per op
  const float* bsrc[2]; int buo[2];
  #pragma unroll
  for (int i = 0; i < 2; i++) {
    int u = tid + i * 256;
    buo[i] = u;
    int cb2 = u >> 6, lb = u & 63;
    int row = c0 + (cb2 >> 1) * 16 + (lb & 15);
    bsrc[i] = WG + (size_t)row * H_DIM + (cb2 & 1) * 32 + (lb >> 4) * 8;
  }
  ptrdiff_t dWU = WU - WG;

  f32x4 accg[4][2] = {}, accu[4][2] = {};
  // register set A (even phases)
  bf16x8 raA[4]; float4 gA[2][2], uA[2][2];
  // register set B (odd phases)
  bf16x8 raB[4]; float4 gB[2][2], uB[2][2];

  auto loadS0 = [&](int p) {
    #pragma unroll
    for (int j = 0; j < 4; j++) raA[j] = abase[j][(size_t)(2 * p) * 64];
    #pragma unroll
    for (int i = 0; i < 2; i++) {
      const float* pg = bsrc[i] + p * 64;
      gA[i][0] = *(const float4*)pg;
      gA[i][1] = *(const float4*)(pg + 4);
      uA[i][0] = *(const float4*)(pg + dWU);
      uA[i][1] = *(const float4*)(pg + dWU + 4);
    }
  };
  auto loadS1 = [&](int p) {
    #pragma unroll
    for (int j = 0; j < 4; j++) raB[j] = abase[j][(size_t)(2 * p) * 64];
    #pragma unroll
    for (int i = 0; i < 2; i++) {
      const float* pg = bsrc[i] + p * 64;
      gB[i][0] = *(const float4*)pg;
      gB[i][1] = *(const float4*)(pg + 4);
      uB[i][0] = *(const float4*)(pg + dWU);
      uB[i][1] = *(const float4*)(pg + dWU + 4);
    }
  };
  auto storeS0 = [&](int b) {
    char* pb = (char*)sm[b];
    #pragma unroll
    for (int j = 0; j < 4; j++)
      *(bf16x8*)(pb + auo[j] * 16) = raA[j];
    #pragma unroll
    for (int i = 0; i < 2; i++) {
      *(bf16x8*)(pb + 16384 + buo[i] * 16) = cvt8(gA[i][0], gA[i][1]);
      *(bf16x8*)(pb + 24576 + buo[i] * 16) = cvt8(uA[i][0], uA[i][1]);
    }
  };
  auto storeS1 = [&](int b) {
    char* pb = (char*)sm[b];
    #pragma unroll
    for (int j = 0; j < 4; j++)
      *(bf16x8*)(pb + auo[j] * 16) = raB[j];
    #pragma unroll
    for (int i = 0; i < 2; i++) {
      *(bf16x8*)(pb + 16384 + buo[i] * 16) = cvt8(gB[i][0], gB[i][1]);
      *(bf16x8*)(pb + 24576 + buo[i] * 16) = cvt8(uB[i][0], uB[i][1]);
    }
  };
  auto compute = [&](int b) {
    char* pb = (char*)sm[b];
    __builtin_amdgcn_s_setprio(1);
    #pragma unroll
    for (int s = 0; s < 2; s++) {
      bf16x8 af[4], bg[2], bu[2];
      #pragma unroll
      for (int mi = 0; mi < 4; mi++)
        af[mi] = *(const bf16x8*)(pb + ((wm * 4 + mi) * 2 + s) * 1024 + l * 16);
      #pragma unroll
      for (int ni = 0; ni < 2; ni++) {
        bg[ni] = *(const bf16x8*)(pb + 16384 + ((wn * 2 + ni) * 2 + s) * 1024 + l * 16);
        bu[ni] = *(const bf16x8*)(pb + 24576 + ((wn * 2 + ni) * 2 + s) * 1024 + l * 16);
      }
      #pragma unroll
      for (int mi = 0; mi < 4; mi++)
        #pragma unroll
        for (int ni = 0; ni < 2; ni++) {
          accg[mi][ni] = __builtin_amdgcn_mfma_f32_16x16x32_bf16(af[mi], bg[ni], accg[mi][ni], 0, 0, 0);
          accu[mi][ni] = __builtin_amdgcn_mfma_f32_16x16x32_bf16(af[mi], bu[ni], accu[mi][ni], 0, 0, 0);
        }
    }
    __builtin_amdgcn_s_setprio(0);
  };

  loadS0(0); loadS1(1);
  storeS0(0);
  asm volatile("s_waitcnt lgkmcnt(0)" ::: "memory");
  __builtin_amdgcn_s_barrier();
  for (int p = 0; p < NP; p += 2) {
    if (p + 2 < NP) loadS0(p + 2);
    compute(0);
    storeS1(1);
    asm volatile("s_waitcnt lgkmcnt(0)" ::: "memory");
    __builtin_amdgcn_s_barrier();
    if (p + 3 < NP) loadS1(p + 3);
    compute(1);
    if (p + 2 < NP) storeS0(0);
    asm volatile("s_waitcnt lgkmcnt(0)" ::: "memory");
    __builtin_amdgcn_s_barrier();
  }

  // epilogue: silu(g)*u -> per-wave bounce (64x32, stride 40) -> FM write
  ushort_t* bw = &sm[0][0] + w * (64 * 40);
  #pragma unroll
  for (int mi = 0; mi < 4; mi++)
    #pragma unroll
    for (int ni = 0; ni < 2; ni++)
      #pragma unroll
      for (int j = 0; j < 4; j++) {
        float gg = accg[mi][ni][j], uu = accu[mi][ni][j];
        float s = (gg / (1.f + expf(-gg))) * uu;
        bw[(mi * 16 + g * 4 + j) * 40 + ni * 16 + fr] = f2bf(s);
      }
  #pragma unroll
  for (int rgi = 0; rgi < 4; rgi++) {
    bf16x8 v = *(const bf16x8*)&bw[(rgi * 16 + (l & 15)) * 40 + (l >> 4) * 8];
    OP[((size_t)(rg0 + wm * 4 + rgi) * KCd + kkd0) * 64 + l] = v;
  }
}

// ---------------- 5) down GEMM: fused cvt, BK=64, single-set pipeline --------
// Tile 64 rows x 128 cols, 4 waves (each 64 rows x 32 cols), phases of K=64.
// LDS/buf: A 8KB [0,8192), B 16KB [8192,24576). Single reg set (no spill).
__global__ __launch_bounds__(256, 2) void down15_kernel(
    const ushort_t* __restrict__ interF, const ushort_t* __restrict__ interS,
    const float* __restrict__ wd_all, const float* __restrict__ swd,
    float* __restrict__ Dr, float* __restrict__ Ds,
    const int* __restrict__ rg2e)
{
  int bid = blockIdx.x;
  int tid = threadIdx.x, w = tid >> 6, l = tid & 63;
  int fr = l & 15, g = l >> 4;

  const bf16x8* AF; const float* WD;
  float* DO;
  int rgA0, c0, NP, KCa, row0;

  if (bid < 4 * NRT64) {
    int cb = bid & 3, rt = bid >> 2;
    int e = rg2e[rt]; if (e < 0) return;
    AF = (const bf16x8*)interF;
    WD = wd_all + (size_t)e * H_DIM * I_DIM;
    rgA0 = rt * 4; c0 = cb * 128;
    KCa = I_DIM >> 5; NP = I_DIM >> 6;   // 32 phases
    row0 = rt * 64;
    DO = Dr;
  } else {
    int b2 = bid - 4 * NRT64;
    int cb = b2 & 3, rt = b2 >> 2;
    AF = (const bf16x8*)interS;
    WD = swd;
    rgA0 = rt * 4; c0 = cb * 128;
    KCa = IS_DIM >> 5; NP = IS_DIM >> 6; // 16 phases
    row0 = rt * 64;
    DO = Ds;
  }
  int Kd = KCa * 32;   // row length in floats

  __shared__ ushort_t sm[2][12288];   // 48 KB

  // A staging: 512 units (8 chunks: ca = rga*2+kc), 2 per thread
  const bf16x8* abase[2]; int auo[2];
  #pragma unroll
  for (int j = 0; j < 2; j++) {
    int u = tid + j * 256;
    auo[j] = u;
    int ca = u >> 6, la = u & 63;
    abase[j] = AF + ((size_t)(rgA0 + (ca >> 1)) * KCa + (ca & 1)) * 64 + la;
  }
  // B staging: 1024 units (16 chunks), 4 per thread
  const float* bsrc[4]; int buo[4];
  #pragma unroll
  for (int i = 0; i < 4; i++) {
    int u = tid + i * 256;
    buo[i] = u;
    int cb2 = u >> 6, lb = u & 63;
    int row = c0 + (cb2 >> 1) * 16 + (lb & 15);
    bsrc[i] = WD + (size_t)row * Kd + (cb2 & 1) * 32 + (lb >> 4) * 8;
  }

  f32x4 acc[4][2] = {};
  bf16x8 ra[2];
  float4 rb[4][2];

  auto load = [&](int p) {
    #pragma unroll
    for (int j = 0; j < 2; j++) ra[j] = abase[j][(size_t)(2 * p) * 64];
    #pragma unroll
    for (int i = 0; i < 4; i++) {
      const float* pg = bsrc[i] + p * 64;
      rb[i][0] = *(const float4*)pg;
      rb[i][1] = *(const float4*)(pg + 4);
    }
  };
  auto store = [&](int b) {
    char* pb = (char*)sm[b];
    #pragma unroll
    for (int j = 0; j < 2; j++)
      *(bf16x8*)(pb + auo[j] * 16) = ra[j];
    #pragma unroll
    for (int i = 0; i < 4; i++)
      *(bf16x8*)(pb + 8192 + buo[i] * 16) = cvt8(rb[i][0], rb[i][1]);
  };
  auto compute = [&](int b) {
    char* pb = (char*)sm[b];
    __builtin_amdgcn_s_setprio(1);
    #pragma unroll
    for (int s = 0; s < 2; s++) {
      bf16x8 af[4], bf[2];
      #pragma unroll
      for (int mi = 0; mi < 4; mi++)
        af[mi] = *(const bf16x8*)(pb + (mi * 2 + s) * 1024 + l * 16);
      #pragma unroll
      for (int ni = 0; ni < 2; ni++)
        bf[ni] = *(const bf16x8*)(pb + 8192 + ((w * 2 + ni) * 2 + s) * 1024 + l * 16);
      #pragma unroll
      for (int mi = 0; mi < 4; mi++)
        #pragma unroll
        for (int ni = 0; ni < 2; ni++)
          acc[mi][ni] = __builtin_amdgcn_mfma_f32_16x16x32_bf16(af[mi], bf[ni], acc[mi][ni], 0, 0, 0);
    }
    __builtin_amdgcn_s_setprio(0);
  };

  load(0);
  store(0);
  asm volatile("s_waitcnt lgkmcnt(0)" ::: "memory");
  __builtin_amdgcn_s_barrier();
  int cur = 0;
  for (int p = 0; p < NP; p++) {
    if (p + 1 < NP) load(p + 1);
    compute(cur);
    if (p + 1 < NP) store(cur ^ 1);
    asm volatile("s_waitcnt lgkmcnt(0)" ::: "memory");
    __builtin_amdgcn_s_barrier();
    cur ^= 1;
  }

  #pragma unroll
  for (int mi = 0; mi < 4; mi++)
    #pragma unroll
    for (int ni = 0; ni < 2; ni++)
      #pragma unroll
      for (int j = 0; j < 4; j++)
        DO[(size_t)(row0 + mi * 16 + g * 4 + j) * H_DIM + c0 + w * 32 + ni * 16 + fr]
            = acc[mi][ni][j];
}

// ---------------- 6) combine: out[t] = w0*Dr[r0] + w1*Dr[r1] + Ds[t] ----------
__global__ __launch_bounds__(128) void combine_kernel(
    const float* __restrict__ Dr, const float* __restrict__ Ds,
    const int* __restrict__ trow, const float* __restrict__ topk_w,
    float* __restrict__ out)
{
  int t = blockIdx.x, c = threadIdx.x;
  int r0 = trow[t * 2], r1 = trow[t * 2 + 1];
  float w0 = topk_w[t * 2], w1 = topk_w[t * 2 + 1];
  float4 a = ((const float4*)(Dr + (size_t)r0 * H_DIM))[c];
  float4 b = ((const float4*)(Dr + (size_t)r1 * H_DIM))[c];
  float4 s = ((const float4*)(Ds + (size_t)t * H_DIM))[c];
  float4 r;
  r.x = w0 * a.x + w1 * b.x + s.x;
  r.y = w0 * a.y + w1 * b.y + s.y;
  r.z = w0 * a.z + w1 * b.z + s.z;
  r.w = w0 * a.w + w1 * b.w + s.w;
  ((float4*)(out + (size_t)t * H_DIM))[c] = r;
}

// ---------------- launch ----------------
extern "C" void kernel_launch(void* const* d_in, const int* in_sizes, int n_in,
                              void* d_out, int out_size, void* d_ws, size_t ws_size,
                              hipStream_t stream) {
  const float* x       = (const float*)d_in[0];
  const float* gate_w  = (const float*)d_in[1];
  const float* w_gate  = (const float*)d_in[2];
  const float* w_up    = (const float*)d_in[3];
  const float* w_down  = (const float*)d_in[4];
  const float* sw_gate = (const float*)d_in[5];
  const float* sw_up   = (const float*)d_in[6];
  const float* sw_down = (const float*)d_in[7];
  float* out = (float*)d_out;

  char* ws = (char*)d_ws;
  int*   counts    = (int*)ws;                      // 16
  int*   cursor    = (int*)(ws + 64);               // 16
  int*   offp      = (int*)(ws + 128);              // 17
  int*   rt2e      = (int*)(ws + 256);              // 48
  int*   rg2e      = (int*)(ws + 448);              // 96
  int*   topk_idx  = (int*)(ws + 832);              // 4096
  float* topk_w    = (float*)(ws + 17216);          // 4096
  int*   trow      = (int*)(ws + 33600);            // 4096
  int*   row_token = (int*)(ws + 49984);            // RPMAX
  size_t off = 49984 + (size_t)RPMAX * 4;
  off = (off + 255) & ~(size_t)255;
  float*    logits = (float*)(ws + off);    off += (size_t)T_TOK * E_NUM * 4;       // 128 KiB
  ushort_t* xgf  = (ushort_t*)(ws + off); off += (size_t)RPMAX * H_DIM * 2;         // 6 MiB
  ushort_t* xsf  = (ushort_t*)(ws + off); off += (size_t)T_TOK * H_DIM * 2;         // 2 MiB
  ushort_t* interF = (ushort_t*)(ws + off); off += (size_t)RPMAX * I_DIM * 2;       // 24 MiB
  ushort_t* interS = (ushort_t*)(ws + off); off += (size_t)T_TOK * IS_DIM * 2;      // 4 MiB
  float*    Dr     = (float*)(ws + off);    off += (size_t)RPMAX * H_DIM * 4;       // 12 MiB
  float*    Ds     = (float*)(ws + off);    off += (size_t)T_TOK * H_DIM * 4;       // 4 MiB

  hipMemsetAsync(counts, 0, 64, stream);
  logits_kernel<<<T_TOK / 16, 256, 0, stream>>>(x, gate_w, logits);
  topk_kernel<<<T_TOK / 256, 256, 0, stream>>>(logits, topk_idx, topk_w, counts);
  offsets_kernel<<<1, 128, 0, stream>>>(counts, offp, cursor, rt2e, rg2e);
  initrows_kernel<<<RPMAX / 256, 256, 0, stream>>>(row_token);
  scatter_kernel<<<(T_TOK + 255) / 256, 256, 0, stream>>>(topk_idx, topk_w, offp, cursor,
                                                          row_token, trow);
  // A-operands into FM bf16
  gatherA_kernel<4><<<RPMAX * H_DIM / 8 / 256, 256, 0, stream>>>(
      x, row_token, xgf, RPMAX * H_DIM / 8, H_DIM);
  gatherA_kernel<4><<<T_TOK * H_DIM / 8 / 256, 256, 0, stream>>>(
      x, nullptr, xsf, T_TOK * H_DIM / 8, H_DIM);

  // GU (fused conversion): routed 32 cb x 48 rt = 1536 + shared 16 x 16 = 256
  gu14_kernel<<<32 * NRT128 + 16 * 16, 256, 0, stream>>>(
      xgf, xsf, w_gate, w_up, sw_gate, sw_up, interF, interS, rt2e);
  // down (fused conversion): routed 4 cb x 96 rt = 384 + shared 4 x 32 = 128
  down15_kernel<<<4 * NRT64 + 4 * 32, 256, 0, stream>>>(
      interF, interS, w_down, sw_down, Dr, Ds, rg2e);
  // combine
  combine_kernel<<<T_TOK, 128, 0, stream>>>(Dr, Ds, trow, topk_w, out);
}

// Round 20
// 185.148 us; speedup vs baseline: 1.6656x; 1.2787x over previous
//
#include <hip/hip_runtime.h>
#include <hip/hip_bf16.h>
#include <math.h>

// ---------------- problem constants ----------------
#define T_TOK 2048
#define H_DIM 512
#define E_NUM 16
#define TOPK  2
#define I_DIM 2048
#define IS_DIM 1024
#define RPMAX 6144             // padded grouped rows (128-aligned per expert)
#define NRT128 (RPMAX / 128)   // 48
#define NRT64  (RPMAX / 64)    // 96

typedef __attribute__((ext_vector_type(8))) short bf16x8;
typedef __attribute__((ext_vector_type(4))) float f32x4;
typedef unsigned short ushort_t;

static __device__ __forceinline__ unsigned short f2bf(float f) {
  unsigned int u = __float_as_uint(f);
  unsigned int r = (u + 0x7fffu + ((u >> 16) & 1u)) >> 16;   // RNE
  return (unsigned short)r;
}

static __device__ __forceinline__ bf16x8 pack8(float4 a, float4 b) {
  bf16x8 v;
  v[0] = (short)f2bf(a.x); v[1] = (short)f2bf(a.y);
  v[2] = (short)f2bf(a.z); v[3] = (short)f2bf(a.w);
  v[4] = (short)f2bf(b.x); v[5] = (short)f2bf(b.y);
  v[6] = (short)f2bf(b.z); v[7] = (short)f2bf(b.w);
  return v;
}

// 2x float4 (8 consecutive fp32) -> one 16B bf16x8 unit via HW cvt_pk (RNE)
static __device__ __forceinline__ bf16x8 cvt8(float4 a, float4 b) {
  __hip_bfloat162 p0 = __float22bfloat162_rn(make_float2(a.x, a.y));
  __hip_bfloat162 p1 = __float22bfloat162_rn(make_float2(a.z, a.w));
  __hip_bfloat162 p2 = __float22bfloat162_rn(make_float2(b.x, b.y));
  __hip_bfloat162 p3 = __float22bfloat162_rn(make_float2(b.z, b.w));
  union { bf16x8 v; unsigned int u[4]; } r;
  r.u[0] = *(unsigned int*)&p0;
  r.u[1] = *(unsigned int*)&p1;
  r.u[2] = *(unsigned int*)&p2;
  r.u[3] = *(unsigned int*)&p3;
  return r.v;
}

// ================= fragment-major (FM) layout =================
// M[R][K] row-major -> chunk c = rg*(K/32) + kk; lane l holds
// M[rg*16 + (l&15)][kk*32 + (l>>4)*8 .. +8] (one bf16x8, 16B).

// ---------------- x fp32 -> FM bf16 with optional token gather ----------------
template <int LKC>
__global__ __launch_bounds__(256) void gatherA_kernel(const float* __restrict__ x,
                                                      const int* __restrict__ row_token,
                                                      ushort_t* __restrict__ d,
                                                      int n8, int K) {
  const int KC = 1 << LKC;
  int i = blockIdx.x * 256 + threadIdx.x;
  int stride = gridDim.x * 256;
  for (; i < n8; i += stride) {
    int l  = i & 63;
    int fi = i >> 6;
    int kk = fi & (KC - 1);
    int rg = fi >> LKC;
    int row = rg * 16 + (l & 15);
    int tok = row_token ? row_token[row] : row;
    bf16x8 v = {};
    if (tok >= 0) {
      const float* p = x + (size_t)tok * K + kk * 32 + (l >> 4) * 8;
      v = pack8(*(const float4*)p, *(const float4*)(p + 4));
    }
    ((bf16x8*)d)[i] = v;
  }
}

// ---------------- 1a) logits GEMV ----------------
__global__ __launch_bounds__(256) void logits_kernel(
    const float* __restrict__ x, const float* __restrict__ gw,
    float* __restrict__ logits)
{
  __shared__ float xs[16][516];
  int tid = threadIdx.x;
  int t0 = blockIdx.x * 16;
  for (int i = tid; i < 2048; i += 256) {
    int tt = i >> 7, q = i & 127;
    float4 v = ((const float4*)(x + (size_t)(t0 + tt) * H_DIM))[q];
    *(float4*)&xs[tt][q * 4] = v;
  }
  __syncthreads();
  int e = tid >> 4, tt = tid & 15;
  const float* gr = gw + (size_t)e * H_DIM;
  const float* xr = &xs[tt][0];
  int kbase = (blockIdx.x & 7) << 6;
  float acc = 0.f;
  #pragma unroll 8
  for (int kk = 0; kk < H_DIM; kk += 4) {
    int k = (kbase + kk) & (H_DIM - 1);
    float4 b = *(const float4*)(gr + k);
    float4 a = *(const float4*)(xr + k);
    acc += a.x * b.x + a.y * b.y + a.z * b.z + a.w * b.w;
  }
  logits[(size_t)(t0 + tt) * E_NUM + e] = acc;
}

// ---------------- 1b) softmax + top2 + histogram ----------------
__global__ __launch_bounds__(256) void topk_kernel(
    const float* __restrict__ logits,
    int* __restrict__ topk_idx, float* __restrict__ topk_w, int* __restrict__ counts)
{
  __shared__ int hist[E_NUM];
  int tid = threadIdx.x;
  if (tid < E_NUM) hist[tid] = 0;
  __syncthreads();
  int t = blockIdx.x * 256 + tid;
  float lg[E_NUM];
  #pragma unroll
  for (int i = 0; i < 4; i++) {
    float4 v = ((const float4*)(logits + (size_t)t * E_NUM))[i];
    lg[i * 4] = v.x; lg[i * 4 + 1] = v.y; lg[i * 4 + 2] = v.z; lg[i * 4 + 3] = v.w;
  }
  float mx = lg[0];
  #pragma unroll
  for (int i = 1; i < E_NUM; i++) mx = fmaxf(mx, lg[i]);
  float sc[E_NUM];
  float sum = 0.f;
  #pragma unroll
  for (int i = 0; i < E_NUM; i++) { sc[i] = expf(lg[i] - mx); sum += sc[i]; }
  float inv = 1.f / sum;
  float m1 = -1.f, m2 = -1.f; int i1 = 0, i2 = 0;
  #pragma unroll
  for (int i = 0; i < E_NUM; i++) {
    float s = sc[i] * inv;
    if (s > m1)      { m2 = m1; i2 = i1; m1 = s; i1 = i; }
    else if (s > m2) { m2 = s; i2 = i; }
  }
  topk_idx[t * 2] = i1; topk_idx[t * 2 + 1] = i2;
  topk_w[t * 2] = m1;  topk_w[t * 2 + 1] = m2;
  atomicAdd(&hist[i1], 1);
  atomicAdd(&hist[i2], 1);
  __syncthreads();
  if (tid < E_NUM) atomicAdd(&counts[tid], hist[tid]);
}

// ---------------- 2) 128-aligned padded scan + tile->expert maps ----------------
__global__ void offsets_kernel(const int* __restrict__ counts,
                               int* __restrict__ offp, int* __restrict__ cursor,
                               int* __restrict__ rt2e, int* __restrict__ rg2e)
{
  __shared__ int offs[E_NUM + 1];
  int tid = threadIdx.x;
  if (tid == 0) {
    int acc = 0;
    #pragma unroll
    for (int e = 0; e < E_NUM; e++) {
      offs[e] = acc; offp[e] = acc;
      acc += (counts[e] + 127) & ~127;
    }
    offs[E_NUM] = acc; offp[E_NUM] = acc;
  }
  if (tid < E_NUM) cursor[tid] = 0;
  __syncthreads();
  for (int r = tid; r < NRT128; r += 128) {
    int row = r << 7; int e = -1;
    #pragma unroll
    for (int i = 0; i < E_NUM; i++)
      if (row >= offs[i] && row < offs[i + 1]) e = i;
    rt2e[r] = e;
  }
  for (int r = tid; r < NRT64; r += 128) {
    int row = r << 6; int e = -1;
    #pragma unroll
    for (int i = 0; i < E_NUM; i++)
      if (row >= offs[i] && row < offs[i + 1]) e = i;
    rg2e[r] = e;
  }
}

// ---------------- 2b) init padded row arrays ----------------
__global__ __launch_bounds__(256) void initrows_kernel(int* __restrict__ row_token) {
  int i = blockIdx.x * 256 + threadIdx.x;
  if (i < RPMAX) row_token[i] = -1;
}

// ---------------- 3) scatter (+ inverse map trow) ----------------
__global__ __launch_bounds__(256) void scatter_kernel(
    const int* __restrict__ topk_idx, const float* __restrict__ topk_w,
    const int* __restrict__ offp, int* __restrict__ cursor,
    int* __restrict__ row_token, int* __restrict__ trow)
{
  int t = blockIdx.x * 256 + threadIdx.x;
  if (t >= T_TOK) return;
  #pragma unroll
  for (int k = 0; k < TOPK; k++) {
    int e = topk_idx[t * 2 + k];
    int pos = atomicAdd(&cursor[e], 1);
    int row = offp[e] + pos;
    row_token[row] = t;
    trow[t * 2 + k] = row;
  }
}

// ---------------- 4) GU GEMM: fused cvt, BK=32, 2-set pipeline, 16B writes ---
// Tile 128 rows x 64 cols, 4 waves (wm rows-64, wn cols-32), 16 kk steps.
// LDS/buf 16KB: A [0,8192), Bg [8192,12288), Bu [12288,16384) bytes.
// B staging: thread u loads 8 consecutive fp32, writes ONE 16B FM unit.
__global__ __launch_bounds__(256, 2) void gu15_kernel(
    const ushort_t* __restrict__ xgf, const ushort_t* __restrict__ xsf,
    const float* __restrict__ wg_all, const float* __restrict__ wu_all,
    const float* __restrict__ swg, const float* __restrict__ swu,
    ushort_t* __restrict__ interF, ushort_t* __restrict__ interS,
    const int* __restrict__ rt2e)
{
  const int KC = H_DIM / 32;   // 16
  int bid = blockIdx.x;
  int tid = threadIdx.x, w = tid >> 6, l = tid & 63;
  int wm = w >> 1, wn = w & 1;
  int fr = l & 15, g = l >> 4;

  const bf16x8* AF; const float *WG, *WU;
  bf16x8* OP;
  int rg0, c0, kkd0, KCd;

  if (bid < 32 * NRT128) {
    int cb = bid & 31, rt = bid >> 5;
    int e = rt2e[rt]; if (e < 0) return;
    rg0 = rt * 8;
    AF = (const bf16x8*)xgf;
    WG = wg_all + (size_t)e * I_DIM * H_DIM;
    WU = wu_all + (size_t)e * I_DIM * H_DIM;
    c0 = cb * 64;
    KCd = I_DIM >> 5; kkd0 = cb * 2 + wn;
    OP = (bf16x8*)interF;
  } else {
    int b2 = bid - 32 * NRT128;
    int cb = b2 & 15, rt = b2 >> 4;
    rg0 = rt * 8;
    AF = (const bf16x8*)xsf;
    WG = swg; WU = swu;
    c0 = cb * 64;
    KCd = IS_DIM >> 5; kkd0 = cb * 2 + wn;
    OP = (bf16x8*)interS;
  }

  __shared__ ushort_t sm[2][8192];   // 32 KB

  // A staging: 512 units (8 rowgroup-chunks), 2 per thread, linear writes
  const bf16x8* abase[2]; int au[2];
  #pragma unroll
  for (int j = 0; j < 2; j++) {
    int u = tid + j * 256;
    au[j] = u;
    abase[j] = AF + ((size_t)(rg0 + (u >> 6)) * KC) * 64 + (u & 63);
  }
  // B staging: 256 units per operand, 1 per thread; thread u -> FM unit u.
  // unit u: chunk = u>>6 (rowgroup), lane = u&63 -> row c0+(u>>6)*16+(u&15),
  // k-offset ((u>>4)&3)*8. Load 8 consecutive fp32, write one 16B unit.
  int brow = c0 + ((tid >> 6) << 4) + (tid & 15);
  int bko  = ((tid >> 4) & 3) * 8;
  const float* bgp = WG + (size_t)brow * H_DIM + bko;
  ptrdiff_t dWU = WU - WG;
  int bwo = tid * 16;   // byte offset within plane

  f32x4 accg[4][2] = {}, accu[4][2] = {};
  // set A (even kk), set B (odd kk)
  bf16x8 raA[2]; float4 gA[2], uA[2];
  bf16x8 raB[2]; float4 gB[2], uB[2];

  auto loadS0 = [&](int kk) {
    #pragma unroll
    for (int j = 0; j < 2; j++) raA[j] = abase[j][(size_t)kk * 64];
    const float* p = bgp + kk * 32;
    gA[0] = *(const float4*)p;        gA[1] = *(const float4*)(p + 4);
    uA[0] = *(const float4*)(p + dWU); uA[1] = *(const float4*)(p + dWU + 4);
  };
  auto loadS1 = [&](int kk) {
    #pragma unroll
    for (int j = 0; j < 2; j++) raB[j] = abase[j][(size_t)kk * 64];
    const float* p = bgp + kk * 32;
    gB[0] = *(const float4*)p;        gB[1] = *(const float4*)(p + 4);
    uB[0] = *(const float4*)(p + dWU); uB[1] = *(const float4*)(p + dWU + 4);
  };
  auto storeS0 = [&](int b) {
    char* pb = (char*)sm[b];
    *(bf16x8*)(pb + au[0] * 16) = raA[0];
    *(bf16x8*)(pb + au[1] * 16) = raA[1];
    *(bf16x8*)(pb + 8192  + bwo) = cvt8(gA[0], gA[1]);
    *(bf16x8*)(pb + 12288 + bwo) = cvt8(uA[0], uA[1]);
  };
  auto storeS1 = [&](int b) {
    char* pb = (char*)sm[b];
    *(bf16x8*)(pb + au[0] * 16) = raB[0];
    *(bf16x8*)(pb + au[1] * 16) = raB[1];
    *(bf16x8*)(pb + 8192  + bwo) = cvt8(gB[0], gB[1]);
    *(bf16x8*)(pb + 12288 + bwo) = cvt8(uB[0], uB[1]);
  };
  auto compute = [&](int b) {
    char* pb = (char*)sm[b];
    bf16x8 af[4], bg[2], bu[2];
    #pragma unroll
    for (int mi = 0; mi < 4; mi++)
      af[mi] = *(const bf16x8*)(pb + (wm * 4 + mi) * 1024 + l * 16);
    #pragma unroll
    for (int ni = 0; ni < 2; ni++) {
      bg[ni] = *(const bf16x8*)(pb + 8192  + (wn * 2 + ni) * 1024 + l * 16);
      bu[ni] = *(const bf16x8*)(pb + 12288 + (wn * 2 + ni) * 1024 + l * 16);
    }
    __builtin_amdgcn_s_setprio(1);
    #pragma unroll
    for (int mi = 0; mi < 4; mi++)
      #pragma unroll
      for (int ni = 0; ni < 2; ni++) {
        accg[mi][ni] = __builtin_amdgcn_mfma_f32_16x16x32_bf16(af[mi], bg[ni], accg[mi][ni], 0, 0, 0);
        accu[mi][ni] = __builtin_amdgcn_mfma_f32_16x16x32_bf16(af[mi], bu[ni], accu[mi][ni], 0, 0, 0);
      }
    __builtin_amdgcn_s_setprio(0);
  };

  loadS0(0); loadS1(1);
  storeS0(0);
  asm volatile("s_waitcnt lgkmcnt(0)" ::: "memory");
  __builtin_amdgcn_s_barrier();
  for (int kk = 0; kk < KC; kk += 2) {
    if (kk + 2 < KC) loadS0(kk + 2);
    compute(0);
    storeS1(1);
    asm volatile("s_waitcnt lgkmcnt(0)" ::: "memory");
    __builtin_amdgcn_s_barrier();
    if (kk + 3 < KC) loadS1(kk + 3);
    compute(1);
    if (kk + 2 < KC) storeS0(0);
    asm volatile("s_waitcnt lgkmcnt(0)" ::: "memory");
    __builtin_amdgcn_s_barrier();
  }

  // epilogue: silu(g)*u -> per-wave bounce (64x32, stride 40) -> FM write
  ushort_t* bw = &sm[0][0] + w * (64 * 40);
  #pragma unroll
  for (int mi = 0; mi < 4; mi++)
    #pragma unroll
    for (int ni = 0; ni < 2; ni++)
      #pragma unroll
      for (int j = 0; j < 4; j++) {
        float gg = accg[mi][ni][j], uu = accu[mi][ni][j];
        float s = (gg / (1.f + expf(-gg))) * uu;
        bw[(mi * 16 + g * 4 + j) * 40 + ni * 16 + fr] = f2bf(s);
      }
  #pragma unroll
  for (int rgi = 0; rgi < 4; rgi++) {
    bf16x8 v = *(const bf16x8*)&bw[(rgi * 16 + (l & 15)) * 40 + (l >> 4) * 8];
    OP[((size_t)(rg0 + wm * 4 + rgi) * KCd + kkd0) * 64 + l] = v;
  }
}

// ---------------- 5) down GEMM: fused cvt, BK=64, 2-set pipeline, 16B writes -
// Tile 64 rows x 128 cols, 4 waves (each 64 rows x 32 cols), steps of K=64.
// LDS/buf 24KB: A [0,8192), B [8192,24576) bytes.
__global__ __launch_bounds__(256, 2) void down16_kernel(
    const ushort_t* __restrict__ interF, const ushort_t* __restrict__ interS,
    const float* __restrict__ wd_all, const float* __restrict__ swd,
    float* __restrict__ Dr, float* __restrict__ Ds,
    const int* __restrict__ rg2e)
{
  int bid = blockIdx.x;
  int tid = threadIdx.x, w = tid >> 6, l = tid & 63;
  int fr = l & 15, g = l >> 4;

  const bf16x8* AF; const float* WD;
  float* DO;
  int rgA0, c0, NP, KCa, row0;

  if (bid < 4 * NRT64) {
    int cb = bid & 3, rt = bid >> 2;
    int e = rg2e[rt]; if (e < 0) return;
    AF = (const bf16x8*)interF;
    WD = wd_all + (size_t)e * H_DIM * I_DIM;
    rgA0 = rt * 4; c0 = cb * 128;
    KCa = I_DIM >> 5; NP = I_DIM >> 6;   // 32 steps
    row0 = rt * 64;
    DO = Dr;
  } else {
    int b2 = bid - 4 * NRT64;
    int cb = b2 & 3, rt = b2 >> 2;
    AF = (const bf16x8*)interS;
    WD = swd;
    rgA0 = rt * 4; c0 = cb * 128;
    KCa = IS_DIM >> 5; NP = IS_DIM >> 6; // 16 steps
    row0 = rt * 64;
    DO = Ds;
  }
  int Kd = KCa * 32;   // row length in floats

  __shared__ ushort_t sm[2][12288];   // 48 KB

  // A staging: 512 units (8 chunks: ca = rga*2+kc), 2 per thread, linear
  const bf16x8* abase[2]; int au[2];
  #pragma unroll
  for (int j = 0; j < 2; j++) {
    int u = tid + j * 256;
    au[j] = u;
    int ca = u >> 6;
    abase[j] = AF + ((size_t)(rgA0 + (ca >> 1)) * KCa + (ca & 1)) * 64 + (u & 63);
  }
  // B staging: 1024 units (16 chunks = 8 rowgroups x 2 kc), 4 per thread.
  // unit u: cb2 = u>>6, lb = u&63 -> row c0+(cb2>>1)*16+(lb&15),
  // k-off (cb2&1)*32 + ((lb>>4))*8. One 16B write per unit.
  const float* bsrc[4]; int buo[4];
  #pragma unroll
  for (int i = 0; i < 4; i++) {
    int u = tid + i * 256;
    buo[i] = u * 16;
    int cb2 = u >> 6, lb = u & 63;
    int row = c0 + (cb2 >> 1) * 16 + (lb & 15);
    bsrc[i] = WD + (size_t)row * Kd + (cb2 & 1) * 32 + (lb >> 4) * 8;
  }

  f32x4 acc[4][2] = {};
  bf16x8 raA[2]; float4 bA[4][2];
  bf16x8 raB[2]; float4 bB[4][2];

  auto loadS0 = [&](int p) {
    #pragma unroll
    for (int j = 0; j < 2; j++) raA[j] = abase[j][(size_t)(2 * p) * 64];
    #pragma unroll
    for (int i = 0; i < 4; i++) {
      const float* pg = bsrc[i] + p * 64;
      bA[i][0] = *(const float4*)pg;
      bA[i][1] = *(const float4*)(pg + 4);
    }
  };
  auto loadS1 = [&](int p) {
    #pragma unroll
    for (int j = 0; j < 2; j++) raB[j] = abase[j][(size_t)(2 * p) * 64];
    #pragma unroll
    for (int i = 0; i < 4; i++) {
      const float* pg = bsrc[i] + p * 64;
      bB[i][0] = *(const float4*)pg;
      bB[i][1] = *(const float4*)(pg + 4);
    }
  };
  auto storeS0 = [&](int b) {
    char* pb = (char*)sm[b];
    *(bf16x8*)(pb + au[0] * 16) = raA[0];
    *(bf16x8*)(pb + au[1] * 16) = raA[1];
    #pragma unroll
    for (int i = 0; i < 4; i++)
      *(bf16x8*)(pb + 8192 + buo[i]) = cvt8(bA[i][0], bA[i][1]);
  };
  auto storeS1 = [&](int b) {
    char* pb = (char*)sm[b];
    *(bf16x8*)(pb + au[0] * 16) = raB[0];
    *(bf16x8*)(pb + au[1] * 16) = raB[1];
    #pragma unroll
    for (int i = 0; i < 4; i++)
      *(bf16x8*)(pb + 8192 + buo[i]) = cvt8(bB[i][0], bB[i][1]);
  };
  auto compute = [&](int b) {
    char* pb = (char*)sm[b];
    __builtin_amdgcn_s_setprio(1);
    #pragma unroll
    for (int s = 0; s < 2; s++) {
      bf16x8 af[4], bf[2];
      #pragma unroll
      for (int mi = 0; mi < 4; mi++)
        af[mi] = *(const bf16x8*)(pb + (mi * 2 + s) * 1024 + l * 16);
      #pragma unroll
      for (int ni = 0; ni < 2; ni++)
        bf[ni] = *(const bf16x8*)(pb + 8192 + ((w * 2 + ni) * 2 + s) * 1024 + l * 16);
      #pragma unroll
      for (int mi = 0; mi < 4; mi++)
        #pragma unroll
        for (int ni = 0; ni < 2; ni++)
          acc[mi][ni] = __builtin_amdgcn_mfma_f32_16x16x32_bf16(af[mi], bf[ni], acc[mi][ni], 0, 0, 0);
    }
    __builtin_amdgcn_s_setprio(0);
  };

  loadS0(0); loadS1(1);
  storeS0(0);
  asm volatile("s_waitcnt lgkmcnt(0)" ::: "memory");
  __builtin_amdgcn_s_barrier();
  for (int p = 0; p < NP; p += 2) {
    if (p + 2 < NP) loadS0(p + 2);
    compute(0);
    storeS1(1);
    asm volatile("s_waitcnt lgkmcnt(0)" ::: "memory");
    __builtin_amdgcn_s_barrier();
    if (p + 3 < NP) loadS1(p + 3);
    compute(1);
    if (p + 2 < NP) storeS0(0);
    asm volatile("s_waitcnt lgkmcnt(0)" ::: "memory");
    __builtin_amdgcn_s_barrier();
  }

  #pragma unroll
  for (int mi = 0; mi < 4; mi++)
    #pragma unroll
    for (int ni = 0; ni < 2; ni++)
      #pragma unroll
      for (int j = 0; j < 4; j++)
        DO[(size_t)(row0 + mi * 16 + g * 4 + j) * H_DIM + c0 + w * 32 + ni * 16 + fr]
            = acc[mi][ni][j];
}

// ---------------- 6) combine: out[t] = w0*Dr[r0] + w1*Dr[r1] + Ds[t] ----------
__global__ __launch_bounds__(128) void combine_kernel(
    const float* __restrict__ Dr, const float* __restrict__ Ds,
    const int* __restrict__ trow, const float* __restrict__ topk_w,
    float* __restrict__ out)
{
  int t = blockIdx.x, c = threadIdx.x;
  int r0 = trow[t * 2], r1 = trow[t * 2 + 1];
  float w0 = topk_w[t * 2], w1 = topk_w[t * 2 + 1];
  float4 a = ((const float4*)(Dr + (size_t)r0 * H_DIM))[c];
  float4 b = ((const float4*)(Dr + (size_t)r1 * H_DIM))[c];
  float4 s = ((const float4*)(Ds + (size_t)t * H_DIM))[c];
  float4 r;
  r.x = w0 * a.x + w1 * b.x + s.x;
  r.y = w0 * a.y + w1 * b.y + s.y;
  r.z = w0 * a.z + w1 * b.z + s.z;
  r.w = w0 * a.w + w1 * b.w + s.w;
  ((float4*)(out + (size_t)t * H_DIM))[c] = r;
}

// ---------------- launch ----------------
extern "C" void kernel_launch(void* const* d_in, const int* in_sizes, int n_in,
                              void* d_out, int out_size, void* d_ws, size_t ws_size,
                              hipStream_t stream) {
  const float* x       = (const float*)d_in[0];
  const float* gate_w  = (const float*)d_in[1];
  const float* w_gate  = (const float*)d_in[2];
  const float* w_up    = (const float*)d_in[3];
  const float* w_down  = (const float*)d_in[4];
  const float* sw_gate = (const float*)d_in[5];
  const float* sw_up   = (const float*)d_in[6];
  const float* sw_down = (const float*)d_in[7];
  float* out = (float*)d_out;

  char* ws = (char*)d_ws;
  int*   counts    = (int*)ws;                      // 16
  int*   cursor    = (int*)(ws + 64);               // 16
  int*   offp      = (int*)(ws + 128);              // 17
  int*   rt2e      = (int*)(ws + 256);              // 48
  int*   rg2e      = (int*)(ws + 448);              // 96
  int*   topk_idx  = (int*)(ws + 832);              // 4096
  float* topk_w    = (float*)(ws + 17216);          // 4096
  int*   trow      = (int*)(ws + 33600);            // 4096
  int*   row_token = (int*)(ws + 49984);            // RPMAX
  size_t off = 49984 + (size_t)RPMAX * 4;
  off = (off + 255) & ~(size_t)255;
  float*    logits = (float*)(ws + off);    off += (size_t)T_TOK * E_NUM * 4;       // 128 KiB
  ushort_t* xgf  = (ushort_t*)(ws + off); off += (size_t)RPMAX * H_DIM * 2;         // 6 MiB
  ushort_t* xsf  = (ushort_t*)(ws + off); off += (size_t)T_TOK * H_DIM * 2;         // 2 MiB
  ushort_t* interF = (ushort_t*)(ws + off); off += (size_t)RPMAX * I_DIM * 2;       // 24 MiB
  ushort_t* interS = (ushort_t*)(ws + off); off += (size_t)T_TOK * IS_DIM * 2;      // 4 MiB
  float*    Dr     = (float*)(ws + off);    off += (size_t)RPMAX * H_DIM * 4;       // 12 MiB
  float*    Ds     = (float*)(ws + off);    off += (size_t)T_TOK * H_DIM * 4;       // 4 MiB

  hipMemsetAsync(counts, 0, 64, stream);
  logits_kernel<<<T_TOK / 16, 256, 0, stream>>>(x, gate_w, logits);
  topk_kernel<<<T_TOK / 256, 256, 0, stream>>>(logits, topk_idx, topk_w, counts);
  offsets_kernel<<<1, 128, 0, stream>>>(counts, offp, cursor, rt2e, rg2e);
  initrows_kernel<<<RPMAX / 256, 256, 0, stream>>>(row_token);
  scatter_kernel<<<(T_TOK + 255) / 256, 256, 0, stream>>>(topk_idx, topk_w, offp, cursor,
                                                          row_token, trow);
  // A-operands into FM bf16
  gatherA_kernel<4><<<RPMAX * H_DIM / 8 / 256, 256, 0, stream>>>(
      x, row_token, xgf, RPMAX * H_DIM / 8, H_DIM);
  gatherA_kernel<4><<<T_TOK * H_DIM / 8 / 256, 256, 0, stream>>>(
      x, nullptr, xsf, T_TOK * H_DIM / 8, H_DIM);

  // GU (fused conversion): routed 32 cb x 48 rt = 1536 + shared 16 x 16 = 256
  gu15_kernel<<<32 * NRT128 + 16 * 16, 256, 0, stream>>>(
      xgf, xsf, w_gate, w_up, sw_gate, sw_up, interF, interS, rt2e);
  // down (fused conversion): routed 4 cb x 96 rt = 384 + shared 4 x 32 = 128
  down16_kernel<<<4 * NRT64 + 4 * 32, 256, 0, stream>>>(
      interF, interS, w_down, sw_down, Dr, Ds, rg2e);
  // combine
  combine_kernel<<<T_TOK, 128, 0, stream>>>(Dr, Ds, trow, topk_w, out);
}

// Round 21
// 156.620 us; speedup vs baseline: 1.9690x; 1.1822x over previous
//
#include <hip/hip_runtime.h>
#include <hip/hip_bf16.h>
#include <math.h>

// ---------------- problem constants ----------------
#define T_TOK 2048
#define H_DIM 512
#define E_NUM 16
#define TOPK  2
#define I_DIM 2048
#define IS_DIM 1024
#define RPMAX 6144             // padded grouped rows (128-aligned per expert)
#define NRT128 (RPMAX / 128)   // 48
#define NRT64  (RPMAX / 64)    // 96

typedef __attribute__((ext_vector_type(8))) short bf16x8;
typedef __attribute__((ext_vector_type(4))) float f32x4;
typedef unsigned short ushort_t;

static __device__ __forceinline__ unsigned short f2bf(float f) {
  unsigned int u = __float_as_uint(f);
  unsigned int r = (u + 0x7fffu + ((u >> 16) & 1u)) >> 16;   // RNE
  return (unsigned short)r;
}

static __device__ __forceinline__ bf16x8 pack8(float4 a, float4 b) {
  bf16x8 v;
  v[0] = (short)f2bf(a.x); v[1] = (short)f2bf(a.y);
  v[2] = (short)f2bf(a.z); v[3] = (short)f2bf(a.w);
  v[4] = (short)f2bf(b.x); v[5] = (short)f2bf(b.y);
  v[6] = (short)f2bf(b.z); v[7] = (short)f2bf(b.w);
  return v;
}

// 2x float4 (8 consecutive fp32) -> one 16B bf16x8 unit via HW cvt_pk (RNE)
static __device__ __forceinline__ bf16x8 cvt8(float4 a, float4 b) {
  __hip_bfloat162 p0 = __float22bfloat162_rn(make_float2(a.x, a.y));
  __hip_bfloat162 p1 = __float22bfloat162_rn(make_float2(a.z, a.w));
  __hip_bfloat162 p2 = __float22bfloat162_rn(make_float2(b.x, b.y));
  __hip_bfloat162 p3 = __float22bfloat162_rn(make_float2(b.z, b.w));
  union { bf16x8 v; unsigned int u[4]; } r;
  r.u[0] = *(unsigned int*)&p0;
  r.u[1] = *(unsigned int*)&p1;
  r.u[2] = *(unsigned int*)&p2;
  r.u[3] = *(unsigned int*)&p3;
  return r.v;
}

// ================= fragment-major (FM) layout =================
// M[R][K] row-major -> chunk c = rg*(K/32) + kk; lane l holds
// M[rg*16 + (l&15)][kk*32 + (l>>4)*8 .. +8] (one bf16x8, 16B).

// ---------------- x fp32 -> FM bf16 with optional token gather ----------------
template <int LKC>
__global__ __launch_bounds__(256) void gatherA_kernel(const float* __restrict__ x,
                                                      const int* __restrict__ row_token,
                                                      ushort_t* __restrict__ d,
                                                      int n8, int K) {
  const int KC = 1 << LKC;
  int i = blockIdx.x * 256 + threadIdx.x;
  int stride = gridDim.x * 256;
  for (; i < n8; i += stride) {
    int l  = i & 63;
    int fi = i >> 6;
    int kk = fi & (KC - 1);
    int rg = fi >> LKC;
    int row = rg * 16 + (l & 15);
    int tok = row_token ? row_token[row] : row;
    bf16x8 v = {};
    if (tok >= 0) {
      const float* p = x + (size_t)tok * K + kk * 32 + (l >> 4) * 8;
      v = pack8(*(const float4*)p, *(const float4*)(p + 4));
    }
    ((bf16x8*)d)[i] = v;
  }
}

// ---------------- 1a) logits GEMV ----------------
__global__ __launch_bounds__(256) void logits_kernel(
    const float* __restrict__ x, const float* __restrict__ gw,
    float* __restrict__ logits)
{
  __shared__ float xs[16][516];
  int tid = threadIdx.x;
  int t0 = blockIdx.x * 16;
  for (int i = tid; i < 2048; i += 256) {
    int tt = i >> 7, q = i & 127;
    float4 v = ((const float4*)(x + (size_t)(t0 + tt) * H_DIM))[q];
    *(float4*)&xs[tt][q * 4] = v;
  }
  __syncthreads();
  int e = tid >> 4, tt = tid & 15;
  const float* gr = gw + (size_t)e * H_DIM;
  const float* xr = &xs[tt][0];
  int kbase = (blockIdx.x & 7) << 6;
  float acc = 0.f;
  #pragma unroll 8
  for (int kk = 0; kk < H_DIM; kk += 4) {
    int k = (kbase + kk) & (H_DIM - 1);
    float4 b = *(const float4*)(gr + k);
    float4 a = *(const float4*)(xr + k);
    acc += a.x * b.x + a.y * b.y + a.z * b.z + a.w * b.w;
  }
  logits[(size_t)(t0 + tt) * E_NUM + e] = acc;
}

// ---------------- 1b) softmax + top2 + histogram ----------------
__global__ __launch_bounds__(256) void topk_kernel(
    const float* __restrict__ logits,
    int* __restrict__ topk_idx, float* __restrict__ topk_w, int* __restrict__ counts)
{
  __shared__ int hist[E_NUM];
  int tid = threadIdx.x;
  if (tid < E_NUM) hist[tid] = 0;
  __syncthreads();
  int t = blockIdx.x * 256 + tid;
  float lg[E_NUM];
  #pragma unroll
  for (int i = 0; i < 4; i++) {
    float4 v = ((const float4*)(logits + (size_t)t * E_NUM))[i];
    lg[i * 4] = v.x; lg[i * 4 + 1] = v.y; lg[i * 4 + 2] = v.z; lg[i * 4 + 3] = v.w;
  }
  float mx = lg[0];
  #pragma unroll
  for (int i = 1; i < E_NUM; i++) mx = fmaxf(mx, lg[i]);
  float sc[E_NUM];
  float sum = 0.f;
  #pragma unroll
  for (int i = 0; i < E_NUM; i++) { sc[i] = expf(lg[i] - mx); sum += sc[i]; }
  float inv = 1.f / sum;
  float m1 = -1.f, m2 = -1.f; int i1 = 0, i2 = 0;
  #pragma unroll
  for (int i = 0; i < E_NUM; i++) {
    float s = sc[i] * inv;
    if (s > m1)      { m2 = m1; i2 = i1; m1 = s; i1 = i; }
    else if (s > m2) { m2 = s; i2 = i; }
  }
  topk_idx[t * 2] = i1; topk_idx[t * 2 + 1] = i2;
  topk_w[t * 2] = m1;  topk_w[t * 2 + 1] = m2;
  atomicAdd(&hist[i1], 1);
  atomicAdd(&hist[i2], 1);
  __syncthreads();
  if (tid < E_NUM) atomicAdd(&counts[tid], hist[tid]);
}

// ---------------- 2) 128-aligned padded scan + tile->expert maps ----------------
__global__ void offsets_kernel(const int* __restrict__ counts,
                               int* __restrict__ offp, int* __restrict__ cursor,
                               int* __restrict__ rt2e, int* __restrict__ rg2e)
{
  __shared__ int offs[E_NUM + 1];
  int tid = threadIdx.x;
  if (tid == 0) {
    int acc = 0;
    #pragma unroll
    for (int e = 0; e < E_NUM; e++) {
      offs[e] = acc; offp[e] = acc;
      acc += (counts[e] + 127) & ~127;
    }
    offs[E_NUM] = acc; offp[E_NUM] = acc;
  }
  if (tid < E_NUM) cursor[tid] = 0;
  __syncthreads();
  for (int r = tid; r < NRT128; r += 128) {
    int row = r << 7; int e = -1;
    #pragma unroll
    for (int i = 0; i < E_NUM; i++)
      if (row >= offs[i] && row < offs[i + 1]) e = i;
    rt2e[r] = e;
  }
  for (int r = tid; r < NRT64; r += 128) {
    int row = r << 6; int e = -1;
    #pragma unroll
    for (int i = 0; i < E_NUM; i++)
      if (row >= offs[i] && row < offs[i + 1]) e = i;
    rg2e[r] = e;
  }
}

// ---------------- 2b) init padded row arrays ----------------
__global__ __launch_bounds__(256) void initrows_kernel(int* __restrict__ row_token) {
  int i = blockIdx.x * 256 + threadIdx.x;
  if (i < RPMAX) row_token[i] = -1;
}

// ---------------- 3) scatter (+ inverse map trow) ----------------
__global__ __launch_bounds__(256) void scatter_kernel(
    const int* __restrict__ topk_idx, const float* __restrict__ topk_w,
    const int* __restrict__ offp, int* __restrict__ cursor,
    int* __restrict__ row_token, int* __restrict__ trow)
{
  int t = blockIdx.x * 256 + threadIdx.x;
  if (t >= T_TOK) return;
  #pragma unroll
  for (int k = 0; k < TOPK; k++) {
    int e = topk_idx[t * 2 + k];
    int pos = atomicAdd(&cursor[e], 1);
    int row = offp[e] + pos;
    row_token[row] = t;
    trow[t * 2 + k] = row;
  }
}

// ---------------- 4) GU GEMM: fused cvt, BK=32, 2-set pipeline ---------------
// Tile 128 rows x 64 cols, 4 waves (wm rows-64, wn cols-32), 16 kk steps.
// LDS/buf 16KB: A [0,8192), Bg [8192,12288), Bu [12288,16384).
// B staging: 4 threads/row, each loads 8 CONSECUTIVE fp32 (row-coalesced
// 128B/row) and writes ONE 16B FM unit (A-class conflict-free pattern).
__global__ __launch_bounds__(256, 2) void gu16_kernel(
    const ushort_t* __restrict__ xgf, const ushort_t* __restrict__ xsf,
    const float* __restrict__ wg_all, const float* __restrict__ wu_all,
    const float* __restrict__ swg, const float* __restrict__ swu,
    ushort_t* __restrict__ interF, ushort_t* __restrict__ interS,
    const int* __restrict__ rt2e)
{
  const int KC = H_DIM / 32;   // 16
  int bid = blockIdx.x;
  int tid = threadIdx.x, w = tid >> 6, l = tid & 63;
  int wm = w >> 1, wn = w & 1;
  int fr = l & 15, g = l >> 4;

  const bf16x8* AF; const float *WG, *WU;
  bf16x8* OP;
  int rg0, c0, kkd0, KCd;

  if (bid < 32 * NRT128) {
    int cb = bid & 31, rt = bid >> 5;
    int e = rt2e[rt]; if (e < 0) return;
    rg0 = rt * 8;
    AF = (const bf16x8*)xgf;
    WG = wg_all + (size_t)e * I_DIM * H_DIM;
    WU = wu_all + (size_t)e * I_DIM * H_DIM;
    c0 = cb * 64;
    KCd = I_DIM >> 5; kkd0 = cb * 2 + wn;
    OP = (bf16x8*)interF;
  } else {
    int b2 = bid - 32 * NRT128;
    int cb = b2 & 15, rt = b2 >> 4;
    rg0 = rt * 8;
    AF = (const bf16x8*)xsf;
    WG = swg; WU = swu;
    c0 = cb * 64;
    KCd = IS_DIM >> 5; kkd0 = cb * 2 + wn;
    OP = (bf16x8*)interS;
  }

  __shared__ ushort_t sm[2][8192];   // 32 KB

  // A staging: 512 units, 2 per thread, linear writes
  const bf16x8* abase[2]; int au[2];
  #pragma unroll
  for (int j = 0; j < 2; j++) {
    int u = tid + j * 256;
    au[j] = u;
    abase[j] = AF + ((size_t)(rg0 + (u >> 6)) * KC) * 64 + (u & 63);
  }
  // B staging: row r = tid>>2 (4 threads/row), sub = tid&3 -> floats sub*8..+7
  int br = tid >> 2, bsub = tid & 3;
  const float* bgp = WG + (size_t)(c0 + br) * H_DIM + bsub * 8;
  ptrdiff_t dWU = WU - WG;
  int bwo = (((br >> 4) << 6) + (br & 15) + (bsub << 4)) * 16;   // byte off in plane

  f32x4 accg[4][2] = {}, accu[4][2] = {};
  bf16x8 raA[2]; float4 gA[2], uA[2];
  bf16x8 raB[2]; float4 gB[2], uB[2];

  auto loadS0 = [&](int kk) {
    #pragma unroll
    for (int j = 0; j < 2; j++) raA[j] = abase[j][(size_t)kk * 64];
    const float* p = bgp + kk * 32;
    gA[0] = *(const float4*)p;         gA[1] = *(const float4*)(p + 4);
    uA[0] = *(const float4*)(p + dWU); uA[1] = *(const float4*)(p + dWU + 4);
  };
  auto loadS1 = [&](int kk) {
    #pragma unroll
    for (int j = 0; j < 2; j++) raB[j] = abase[j][(size_t)kk * 64];
    const float* p = bgp + kk * 32;
    gB[0] = *(const float4*)p;         gB[1] = *(const float4*)(p + 4);
    uB[0] = *(const float4*)(p + dWU); uB[1] = *(const float4*)(p + dWU + 4);
  };
  auto storeS0 = [&](int b) {
    char* pb = (char*)sm[b];
    *(bf16x8*)(pb + au[0] * 16) = raA[0];
    *(bf16x8*)(pb + au[1] * 16) = raA[1];
    *(bf16x8*)(pb + 8192  + bwo) = cvt8(gA[0], gA[1]);
    *(bf16x8*)(pb + 12288 + bwo) = cvt8(uA[0], uA[1]);
  };
  auto storeS1 = [&](int b) {
    char* pb = (char*)sm[b];
    *(bf16x8*)(pb + au[0] * 16) = raB[0];
    *(bf16x8*)(pb + au[1] * 16) = raB[1];
    *(bf16x8*)(pb + 8192  + bwo) = cvt8(gB[0], gB[1]);
    *(bf16x8*)(pb + 12288 + bwo) = cvt8(uB[0], uB[1]);
  };
  auto compute = [&](int b) {
    char* pb = (char*)sm[b];
    bf16x8 af[4], bg[2], bu[2];
    #pragma unroll
    for (int mi = 0; mi < 4; mi++)
      af[mi] = *(const bf16x8*)(pb + (wm * 4 + mi) * 1024 + l * 16);
    #pragma unroll
    for (int ni = 0; ni < 2; ni++) {
      bg[ni] = *(const bf16x8*)(pb + 8192  + (wn * 2 + ni) * 1024 + l * 16);
      bu[ni] = *(const bf16x8*)(pb + 12288 + (wn * 2 + ni) * 1024 + l * 16);
    }
    __builtin_amdgcn_s_setprio(1);
    #pragma unroll
    for (int mi = 0; mi < 4; mi++)
      #pragma unroll
      for (int ni = 0; ni < 2; ni++) {
        accg[mi][ni] = __builtin_amdgcn_mfma_f32_16x16x32_bf16(af[mi], bg[ni], accg[mi][ni], 0, 0, 0);
        accu[mi][ni] = __builtin_amdgcn_mfma_f32_16x16x32_bf16(af[mi], bu[ni], accu[mi][ni], 0, 0, 0);
      }
    __builtin_amdgcn_s_setprio(0);
  };

  loadS0(0); loadS1(1);
  storeS0(0);
  asm volatile("s_waitcnt lgkmcnt(0)" ::: "memory");
  __builtin_amdgcn_s_barrier();
  for (int kk = 0; kk < KC; kk += 2) {
    if (kk + 2 < KC) loadS0(kk + 2);
    compute(0);
    storeS1(1);
    asm volatile("s_waitcnt lgkmcnt(0)" ::: "memory");
    __builtin_amdgcn_s_barrier();
    if (kk + 3 < KC) loadS1(kk + 3);
    compute(1);
    if (kk + 2 < KC) storeS0(0);
    asm volatile("s_waitcnt lgkmcnt(0)" ::: "memory");
    __builtin_amdgcn_s_barrier();
  }

  // epilogue: silu(g)*u -> per-wave bounce (64x32, stride 40) -> FM write
  ushort_t* bw = &sm[0][0] + w * (64 * 40);
  #pragma unroll
  for (int mi = 0; mi < 4; mi++)
    #pragma unroll
    for (int ni = 0; ni < 2; ni++)
      #pragma unroll
      for (int j = 0; j < 4; j++) {
        float gg = accg[mi][ni][j], uu = accu[mi][ni][j];
        float s = (gg / (1.f + expf(-gg))) * uu;
        bw[(mi * 16 + g * 4 + j) * 40 + ni * 16 + fr] = f2bf(s);
      }
  #pragma unroll
  for (int rgi = 0; rgi < 4; rgi++) {
    bf16x8 v = *(const bf16x8*)&bw[(rgi * 16 + (l & 15)) * 40 + (l >> 4) * 8];
    OP[((size_t)(rg0 + wm * 4 + rgi) * KCd + kkd0) * 64 + l] = v;
  }
}

// ---------------- 5) down GEMM: fused cvt, BK=64, 2-set pipeline -------------
// Tile 64 rows x 128 cols, 4 waves (each 64 rows x 32 cols), steps of K=64.
// LDS/buf 24KB: A [0,8192), B [8192,24576).
// B staging: 8 threads/row, each 8 consecutive fp32 -> one 16B FM unit.
__global__ __launch_bounds__(256, 2) void down17_kernel(
    const ushort_t* __restrict__ interF, const ushort_t* __restrict__ interS,
    const float* __restrict__ wd_all, const float* __restrict__ swd,
    float* __restrict__ Dr, float* __restrict__ Ds,
    const int* __restrict__ rg2e)
{
  int bid = blockIdx.x;
  int tid = threadIdx.x, w = tid >> 6, l = tid & 63;
  int fr = l & 15, g = l >> 4;

  const bf16x8* AF; const float* WD;
  float* DO;
  int rgA0, c0, NP, KCa, row0;

  if (bid < 4 * NRT64) {
    int cb = bid & 3, rt = bid >> 2;
    int e = rg2e[rt]; if (e < 0) return;
    AF = (const bf16x8*)interF;
    WD = wd_all + (size_t)e * H_DIM * I_DIM;
    rgA0 = rt * 4; c0 = cb * 128;
    KCa = I_DIM >> 5; NP = I_DIM >> 6;   // 32 steps
    row0 = rt * 64;
    DO = Dr;
  } else {
    int b2 = bid - 4 * NRT64;
    int cb = b2 & 3, rt = b2 >> 2;
    AF = (const bf16x8*)interS;
    WD = swd;
    rgA0 = rt * 4; c0 = cb * 128;
    KCa = IS_DIM >> 5; NP = IS_DIM >> 6; // 16 steps
    row0 = rt * 64;
    DO = Ds;
  }
  int Kd = KCa * 32;   // row length in floats

  __shared__ ushort_t sm[2][12288];   // 48 KB

  // A staging: 512 units (8 chunks: ca = rga*2+kc), 2 per thread, linear
  const bf16x8* abase[2]; int au[2];
  #pragma unroll
  for (int j = 0; j < 2; j++) {
    int u = tid + j * 256;
    au[j] = u;
    int ca = u >> 6;
    abase[j] = AF + ((size_t)(rgA0 + (ca >> 1)) * KCa + (ca & 1)) * 64 + (u & 63);
  }
  // B staging: 1024 units, 4 per thread; unit: row r = u>>3, sub = u&7,
  // floats sub*8..+7 of the 64-float step. LDS unit = ((r>>4)*2+(sub>>2))*64
  // + (r&15) + (sub&3)*16. Per wave: 8 rows x 256B contiguous.
  const float* bsrc[4]; int buo[4];
  #pragma unroll
  for (int i = 0; i < 4; i++) {
    int u = tid + i * 256;
    int r = u >> 3, sub = u & 7;
    bsrc[i] = WD + (size_t)(c0 + r) * Kd + sub * 8;
    buo[i] = ((((r >> 4) * 2 + (sub >> 2)) << 6) + (r & 15) + ((sub & 3) << 4)) * 16;
  }

  f32x4 acc[4][2] = {};
  bf16x8 raA[2]; float4 bA[4][2];
  bf16x8 raB[2]; float4 bB[4][2];

  auto loadS0 = [&](int p) {
    #pragma unroll
    for (int j = 0; j < 2; j++) raA[j] = abase[j][(size_t)(2 * p) * 64];
    #pragma unroll
    for (int i = 0; i < 4; i++) {
      const float* pg = bsrc[i] + p * 64;
      bA[i][0] = *(const float4*)pg;
      bA[i][1] = *(const float4*)(pg + 4);
    }
  };
  auto loadS1 = [&](int p) {
    #pragma unroll
    for (int j = 0; j < 2; j++) raB[j] = abase[j][(size_t)(2 * p) * 64];
    #pragma unroll
    for (int i = 0; i < 4; i++) {
      const float* pg = bsrc[i] + p * 64;
      bB[i][0] = *(const float4*)pg;
      bB[i][1] = *(const float4*)(pg + 4);
    }
  };
  auto storeS0 = [&](int b) {
    char* pb = (char*)sm[b];
    *(bf16x8*)(pb + au[0] * 16) = raA[0];
    *(bf16x8*)(pb + au[1] * 16) = raA[1];
    #pragma unroll
    for (int i = 0; i < 4; i++)
      *(bf16x8*)(pb + 8192 + buo[i]) = cvt8(bA[i][0], bA[i][1]);
  };
  auto storeS1 = [&](int b) {
    char* pb = (char*)sm[b];
    *(bf16x8*)(pb + au[0] * 16) = raB[0];
    *(bf16x8*)(pb + au[1] * 16) = raB[1];
    #pragma unroll
    for (int i = 0; i < 4; i++)
      *(bf16x8*)(pb + 8192 + buo[i]) = cvt8(bB[i][0], bB[i][1]);
  };
  auto compute = [&](int b) {
    char* pb = (char*)sm[b];
    __builtin_amdgcn_s_setprio(1);
    #pragma unroll
    for (int s = 0; s < 2; s++) {
      bf16x8 af[4], bf[2];
      #pragma unroll
      for (int mi = 0; mi < 4; mi++)
        af[mi] = *(const bf16x8*)(pb + (mi * 2 + s) * 1024 + l * 16);
      #pragma unroll
      for (int ni = 0; ni < 2; ni++)
        bf[ni] = *(const bf16x8*)(pb + 8192 + ((w * 2 + ni) * 2 + s) * 1024 + l * 16);
      #pragma unroll
      for (int mi = 0; mi < 4; mi++)
        #pragma unroll
        for (int ni = 0; ni < 2; ni++)
          acc[mi][ni] = __builtin_amdgcn_mfma_f32_16x16x32_bf16(af[mi], bf[ni], acc[mi][ni], 0, 0, 0);
    }
    __builtin_amdgcn_s_setprio(0);
  };

  loadS0(0); loadS1(1);
  storeS0(0);
  asm volatile("s_waitcnt lgkmcnt(0)" ::: "memory");
  __builtin_amdgcn_s_barrier();
  for (int p = 0; p < NP; p += 2) {
    if (p + 2 < NP) loadS0(p + 2);
    compute(0);
    storeS1(1);
    asm volatile("s_waitcnt lgkmcnt(0)" ::: "memory");
    __builtin_amdgcn_s_barrier();
    if (p + 3 < NP) loadS1(p + 3);
    compute(1);
    if (p + 2 < NP) storeS0(0);
    asm volatile("s_waitcnt lgkmcnt(0)" ::: "memory");
    __builtin_amdgcn_s_barrier();
  }

  #pragma unroll
  for (int mi = 0; mi < 4; mi++)
    #pragma unroll
    for (int ni = 0; ni < 2; ni++)
      #pragma unroll
      for (int j = 0; j < 4; j++)
        DO[(size_t)(row0 + mi * 16 + g * 4 + j) * H_DIM + c0 + w * 32 + ni * 16 + fr]
            = acc[mi][ni][j];
}

// ---------------- 6) combine: out[t] = w0*Dr[r0] + w1*Dr[r1] + Ds[t] ----------
__global__ __launch_bounds__(128) void combine_kernel(
    const float* __restrict__ Dr, const float* __restrict__ Ds,
    const int* __restrict__ trow, const float* __restrict__ topk_w,
    float* __restrict__ out)
{
  int t = blockIdx.x, c = threadIdx.x;
  int r0 = trow[t * 2], r1 = trow[t * 2 + 1];
  float w0 = topk_w[t * 2], w1 = topk_w[t * 2 + 1];
  float4 a = ((const float4*)(Dr + (size_t)r0 * H_DIM))[c];
  float4 b = ((const float4*)(Dr + (size_t)r1 * H_DIM))[c];
  float4 s = ((const float4*)(Ds + (size_t)t * H_DIM))[c];
  float4 r;
  r.x = w0 * a.x + w1 * b.x + s.x;
  r.y = w0 * a.y + w1 * b.y + s.y;
  r.z = w0 * a.z + w1 * b.z + s.z;
  r.w = w0 * a.w + w1 * b.w + s.w;
  ((float4*)(out + (size_t)t * H_DIM))[c] = r;
}

// ---------------- launch ----------------
extern "C" void kernel_launch(void* const* d_in, const int* in_sizes, int n_in,
                              void* d_out, int out_size, void* d_ws, size_t ws_size,
                              hipStream_t stream) {
  const float* x       = (const float*)d_in[0];
  const float* gate_w  = (const float*)d_in[1];
  const float* w_gate  = (const float*)d_in[2];
  const float* w_up    = (const float*)d_in[3];
  const float* w_down  = (const float*)d_in[4];
  const float* sw_gate = (const float*)d_in[5];
  const float* sw_up   = (const float*)d_in[6];
  const float* sw_down = (const float*)d_in[7];
  float* out = (float*)d_out;

  char* ws = (char*)d_ws;
  int*   counts    = (int*)ws;                      // 16
  int*   cursor    = (int*)(ws + 64);               // 16
  int*   offp      = (int*)(ws + 128);              // 17
  int*   rt2e      = (int*)(ws + 256);              // 48
  int*   rg2e      = (int*)(ws + 448);              // 96
  int*   topk_idx  = (int*)(ws + 832);              // 4096
  float* topk_w    = (float*)(ws + 17216);          // 4096
  int*   trow      = (int*)(ws + 33600);            // 4096
  int*   row_token = (int*)(ws + 49984);            // RPMAX
  size_t off = 49984 + (size_t)RPMAX * 4;
  off = (off + 255) & ~(size_t)255;
  float*    logits = (float*)(ws + off);    off += (size_t)T_TOK * E_NUM * 4;       // 128 KiB
  ushort_t* xgf  = (ushort_t*)(ws + off); off += (size_t)RPMAX * H_DIM * 2;         // 6 MiB
  ushort_t* xsf  = (ushort_t*)(ws + off); off += (size_t)T_TOK * H_DIM * 2;         // 2 MiB
  ushort_t* interF = (ushort_t*)(ws + off); off += (size_t)RPMAX * I_DIM * 2;       // 24 MiB
  ushort_t* interS = (ushort_t*)(ws + off); off += (size_t)T_TOK * IS_DIM * 2;      // 4 MiB
  float*    Dr     = (float*)(ws + off);    off += (size_t)RPMAX * H_DIM * 4;       // 12 MiB
  float*    Ds     = (float*)(ws + off);    off += (size_t)T_TOK * H_DIM * 4;       // 4 MiB

  hipMemsetAsync(counts, 0, 64, stream);
  logits_kernel<<<T_TOK / 16, 256, 0, stream>>>(x, gate_w, logits);
  topk_kernel<<<T_TOK / 256, 256, 0, stream>>>(logits, topk_idx, topk_w, counts);
  offsets_kernel<<<1, 128, 0, stream>>>(counts, offp, cursor, rt2e, rg2e);
  initrows_kernel<<<RPMAX / 256, 256, 0, stream>>>(row_token);
  scatter_kernel<<<(T_TOK + 255) / 256, 256, 0, stream>>>(topk_idx, topk_w, offp, cursor,
                                                          row_token, trow);
  // A-operands into FM bf16
  gatherA_kernel<4><<<RPMAX * H_DIM / 8 / 256, 256, 0, stream>>>(
      x, row_token, xgf, RPMAX * H_DIM / 8, H_DIM);
  gatherA_kernel<4><<<T_TOK * H_DIM / 8 / 256, 256, 0, stream>>>(
      x, nullptr, xsf, T_TOK * H_DIM / 8, H_DIM);

  // GU (fused conversion): routed 32 cb x 48 rt = 1536 + shared 16 x 16 = 256
  gu16_kernel<<<32 * NRT128 + 16 * 16, 256, 0, stream>>>(
      xgf, xsf, w_gate, w_up, sw_gate, sw_up, interF, interS, rt2e);
  // down (fused conversion): routed 4 cb x 96 rt = 384 + shared 4 x 32 = 128
  down17_kernel<<<4 * NRT64 + 4 * 32, 256, 0, stream>>>(
      interF, interS, w_down, sw_down, Dr, Ds, rg2e);
  // combine
  combine_kernel<<<T_TOK, 128, 0, stream>>>(Dr, Ds, trow, topk_w, out);
}

// Round 22
// 151.071 us; speedup vs baseline: 2.0413x; 1.0367x over previous
//
#include <hip/hip_runtime.h>
#include <hip/hip_bf16.h>
#include <math.h>

// ---------------- problem constants ----------------
#define T_TOK 2048
#define H_DIM 512
#define E_NUM 16
#define TOPK  2
#define I_DIM 2048
#define IS_DIM 1024
#define RPMAX 6144             // padded grouped rows (128-aligned per expert)
#define NRT128 (RPMAX / 128)   // 48
#define NRT64  (RPMAX / 64)    // 96

typedef __attribute__((ext_vector_type(8))) short bf16x8;
typedef __attribute__((ext_vector_type(4))) float f32x4;
typedef unsigned short ushort_t;

static __device__ __forceinline__ unsigned short f2bf(float f) {
  unsigned int u = __float_as_uint(f);
  unsigned int r = (u + 0x7fffu + ((u >> 16) & 1u)) >> 16;   // RNE
  return (unsigned short)r;
}

static __device__ __forceinline__ bf16x8 pack8(float4 a, float4 b) {
  bf16x8 v;
  v[0] = (short)f2bf(a.x); v[1] = (short)f2bf(a.y);
  v[2] = (short)f2bf(a.z); v[3] = (short)f2bf(a.w);
  v[4] = (short)f2bf(b.x); v[5] = (short)f2bf(b.y);
  v[6] = (short)f2bf(b.z); v[7] = (short)f2bf(b.w);
  return v;
}

// float4 -> 4 bf16 (8B) via HW cvt_pk (RNE)
static __device__ __forceinline__ unsigned long long cvt4(float4 v) {
  __hip_bfloat162 lo = __float22bfloat162_rn(make_float2(v.x, v.y));
  __hip_bfloat162 hi = __float22bfloat162_rn(make_float2(v.z, v.w));
  unsigned int ulo = *(unsigned int*)&lo;
  unsigned int uhi = *(unsigned int*)&hi;
  return ((unsigned long long)uhi << 32) | ulo;
}

// ================= fragment-major (FM) layout =================
// M[R][K] row-major -> chunk c = rg*(K/32) + kk; lane l holds
// M[rg*16 + (l&15)][kk*32 + (l>>4)*8 .. +8] (one bf16x8, 16B).

// ---------------- x fp32 -> FM bf16 with optional token gather ----------------
template <int LKC>
__global__ __launch_bounds__(256) void gatherA_kernel(const float* __restrict__ x,
                                                      const int* __restrict__ row_token,
                                                      ushort_t* __restrict__ d,
                                                      int n8, int K) {
  const int KC = 1 << LKC;
  int i = blockIdx.x * 256 + threadIdx.x;
  int stride = gridDim.x * 256;
  for (; i < n8; i += stride) {
    int l  = i & 63;
    int fi = i >> 6;
    int kk = fi & (KC - 1);
    int rg = fi >> LKC;
    int row = rg * 16 + (l & 15);
    int tok = row_token ? row_token[row] : row;
    bf16x8 v = {};
    if (tok >= 0) {
      const float* p = x + (size_t)tok * K + kk * 32 + (l >> 4) * 8;
      v = pack8(*(const float4*)p, *(const float4*)(p + 4));
    }
    ((bf16x8*)d)[i] = v;
  }
}

// ---------------- 1a) logits GEMV ----------------
__global__ __launch_bounds__(256) void logits_kernel(
    const float* __restrict__ x, const float* __restrict__ gw,
    float* __restrict__ logits)
{
  __shared__ float xs[16][516];
  int tid = threadIdx.x;
  int t0 = blockIdx.x * 16;
  for (int i = tid; i < 2048; i += 256) {
    int tt = i >> 7, q = i & 127;
    float4 v = ((const float4*)(x + (size_t)(t0 + tt) * H_DIM))[q];
    *(float4*)&xs[tt][q * 4] = v;
  }
  __syncthreads();
  int e = tid >> 4, tt = tid & 15;
  const float* gr = gw + (size_t)e * H_DIM;
  const float* xr = &xs[tt][0];
  int kbase = (blockIdx.x & 7) << 6;
  float acc = 0.f;
  #pragma unroll 8
  for (int kk = 0; kk < H_DIM; kk += 4) {
    int k = (kbase + kk) & (H_DIM - 1);
    float4 b = *(const float4*)(gr + k);
    float4 a = *(const float4*)(xr + k);
    acc += a.x * b.x + a.y * b.y + a.z * b.z + a.w * b.w;
  }
  logits[(size_t)(t0 + tt) * E_NUM + e] = acc;
}

// ---------------- 1b) softmax + top2 + histogram ----------------
__global__ __launch_bounds__(256) void topk_kernel(
    const float* __restrict__ logits,
    int* __restrict__ topk_idx, float* __restrict__ topk_w, int* __restrict__ counts)
{
  __shared__ int hist[E_NUM];
  int tid = threadIdx.x;
  if (tid < E_NUM) hist[tid] = 0;
  __syncthreads();
  int t = blockIdx.x * 256 + tid;
  float lg[E_NUM];
  #pragma unroll
  for (int i = 0; i < 4; i++) {
    float4 v = ((const float4*)(logits + (size_t)t * E_NUM))[i];
    lg[i * 4] = v.x; lg[i * 4 + 1] = v.y; lg[i * 4 + 2] = v.z; lg[i * 4 + 3] = v.w;
  }
  float mx = lg[0];
  #pragma unroll
  for (int i = 1; i < E_NUM; i++) mx = fmaxf(mx, lg[i]);
  float sc[E_NUM];
  float sum = 0.f;
  #pragma unroll
  for (int i = 0; i < E_NUM; i++) { sc[i] = expf(lg[i] - mx); sum += sc[i]; }
  float inv = 1.f / sum;
  float m1 = -1.f, m2 = -1.f; int i1 = 0, i2 = 0;
  #pragma unroll
  for (int i = 0; i < E_NUM; i++) {
    float s = sc[i] * inv;
    if (s > m1)      { m2 = m1; i2 = i1; m1 = s; i1 = i; }
    else if (s > m2) { m2 = s; i2 = i; }
  }
  topk_idx[t * 2] = i1; topk_idx[t * 2 + 1] = i2;
  topk_w[t * 2] = m1;  topk_w[t * 2 + 1] = m2;
  atomicAdd(&hist[i1], 1);
  atomicAdd(&hist[i2], 1);
  __syncthreads();
  if (tid < E_NUM) atomicAdd(&counts[tid], hist[tid]);
}

// ---------------- 2) 128-aligned padded scan + tile->expert maps ----------------
__global__ void offsets_kernel(const int* __restrict__ counts,
                               int* __restrict__ offp, int* __restrict__ cursor,
                               int* __restrict__ rt2e, int* __restrict__ rg2e)
{
  __shared__ int offs[E_NUM + 1];
  int tid = threadIdx.x;
  if (tid == 0) {
    int acc = 0;
    #pragma unroll
    for (int e = 0; e < E_NUM; e++) {
      offs[e] = acc; offp[e] = acc;
      acc += (counts[e] + 127) & ~127;
    }
    offs[E_NUM] = acc; offp[E_NUM] = acc;
  }
  if (tid < E_NUM) cursor[tid] = 0;
  __syncthreads();
  for (int r = tid; r < NRT128; r += 128) {
    int row = r << 7; int e = -1;
    #pragma unroll
    for (int i = 0; i < E_NUM; i++)
      if (row >= offs[i] && row < offs[i + 1]) e = i;
    rt2e[r] = e;
  }
  for (int r = tid; r < NRT64; r += 128) {
    int row = r << 6; int e = -1;
    #pragma unroll
    for (int i = 0; i < E_NUM; i++)
      if (row >= offs[i] && row < offs[i + 1]) e = i;
    rg2e[r] = e;
  }
}

// ---------------- 2b) init padded row arrays ----------------
__global__ __launch_bounds__(256) void initrows_kernel(int* __restrict__ row_token) {
  int i = blockIdx.x * 256 + threadIdx.x;
  if (i < RPMAX) row_token[i] = -1;
}

// ---------------- 3) scatter (+ inverse map trow) ----------------
__global__ __launch_bounds__(256) void scatter_kernel(
    const int* __restrict__ topk_idx, const float* __restrict__ topk_w,
    const int* __restrict__ offp, int* __restrict__ cursor,
    int* __restrict__ row_token, int* __restrict__ trow)
{
  int t = blockIdx.x * 256 + threadIdx.x;
  if (t >= T_TOK) return;
  #pragma unroll
  for (int k = 0; k < TOPK; k++) {
    int e = topk_idx[t * 2 + k];
    int pos = atomicAdd(&cursor[e], 1);
    int row = offp[e] + pos;
    row_token[row] = t;
    trow[t * 2 + k] = row;
  }
}

// ---------------- 4) GU GEMM: fused fp32->bf16, LOW-REG 2-buf pipeline -------
// Tile 128 rows x 64 cols, 4 waves (wm rows-64, wn cols-32), BK=32, KC=16.
// acc = accg[4][2]+accu[4][2] = 64 VGPR. LDS 2 x {A 8K, Bg 4K, Bu 4K} = 32KB.
__global__ __launch_bounds__(256, 2) void gu12_kernel(
    const ushort_t* __restrict__ xgf, const ushort_t* __restrict__ xsf,
    const float* __restrict__ wg_all, const float* __restrict__ wu_all,
    const float* __restrict__ swg, const float* __restrict__ swu,
    ushort_t* __restrict__ interF, ushort_t* __restrict__ interS,
    const int* __restrict__ rt2e)
{
  const int KC = H_DIM / 32;   // 16
  int bid = blockIdx.x;
  int tid = threadIdx.x, w = tid >> 6, l = tid & 63;
  int wm = w >> 1, wn = w & 1;
  int fr = l & 15, g = l >> 4;

  const bf16x8* AF; const float *WG, *WU;
  bf16x8* OP;
  int rg0, c0, kkd0, KCd;

  if (bid < 32 * NRT128) {
    int cb = bid & 31, rt = bid >> 5;
    int e = rt2e[rt]; if (e < 0) return;
    rg0 = rt * 8;
    AF = (const bf16x8*)xgf;
    WG = wg_all + (size_t)e * I_DIM * H_DIM;
    WU = wu_all + (size_t)e * I_DIM * H_DIM;
    c0 = cb * 64;
    KCd = I_DIM >> 5; kkd0 = cb * 2 + wn;
    OP = (bf16x8*)interF;
  } else {
    int b2 = bid - 32 * NRT128;
    int cb = b2 & 15, rt = b2 >> 4;
    rg0 = rt * 8;
    AF = (const bf16x8*)xsf;
    WG = swg; WU = swu;
    c0 = cb * 64;
    KCd = IS_DIM >> 5; kkd0 = cb * 2 + wn;
    OP = (bf16x8*)interS;
  }

  // plane layout per buf (bytes): A [0,8192), Bg [8192,12288), Bu [12288,16384)
  __shared__ ushort_t sm[2][8192];   // 32 KB

  // A staging: 2 x 16B per thread
  const bf16x8* abase[2]; int au[2];
  #pragma unroll
  for (int j = 0; j < 2; j++) {
    int u = tid + j * 256;           // 0..511
    au[j] = u;
    abase[j] = AF + ((size_t)(rg0 + (u >> 6)) * KC) * 64 + (u & 63);
  }
  // B staging: 2 float4 per operand per thread (8 lanes/row, 64 rows)
  const float* bgsrc[2]; int bws[2];
  #pragma unroll
  for (int i = 0; i < 2; i++) {
    int f = tid + i * 256;           // 0..511
    int row = f >> 3, q = f & 7;
    bgsrc[i] = WG + (size_t)(c0 + row) * H_DIM + q * 4;
    bws[i] = 8192 + (row >> 4) * 1024 + ((row & 15) + (q >> 1) * 16) * 16 + (q & 1) * 8;
  }
  ptrdiff_t dWU = WU - WG;

  f32x4 accg[4][2] = {}, accu[4][2] = {};
  bf16x8 ra0[2], ra1[2];
  float4 rg0v[2], ru0v[2], rg1v[2], ru1v[2];

  auto loadS0 = [&](int kk) {
    #pragma unroll
    for (int j = 0; j < 2; j++) ra0[j] = abase[j][(size_t)kk * 64];
    #pragma unroll
    for (int i = 0; i < 2; i++) {
      rg0v[i] = *(const float4*)(bgsrc[i] + kk * 32);
      ru0v[i] = *(const float4*)(bgsrc[i] + dWU + kk * 32);
    }
  };
  auto loadS1 = [&](int kk) {
    #pragma unroll
    for (int j = 0; j < 2; j++) ra1[j] = abase[j][(size_t)kk * 64];
    #pragma unroll
    for (int i = 0; i < 2; i++) {
      rg1v[i] = *(const float4*)(bgsrc[i] + kk * 32);
      ru1v[i] = *(const float4*)(bgsrc[i] + dWU + kk * 32);
    }
  };
  auto writeS0 = [&](int b) {
    bf16x8* ap = (bf16x8*)sm[b];
    ap[au[0]] = ra0[0]; ap[au[1]] = ra0[1];
    char* pb = (char*)sm[b];
    #pragma unroll
    for (int i = 0; i < 2; i++) {
      *(unsigned long long*)(pb + bws[i])        = cvt4(rg0v[i]);
      *(unsigned long long*)(pb + bws[i] + 4096) = cvt4(ru0v[i]);
    }
  };
  auto writeS1 = [&](int b) {
    bf16x8* ap = (bf16x8*)sm[b];
    ap[au[0]] = ra1[0]; ap[au[1]] = ra1[1];
    char* pb = (char*)sm[b];
    #pragma unroll
    for (int i = 0; i < 2; i++) {
      *(unsigned long long*)(pb + bws[i])        = cvt4(rg1v[i]);
      *(unsigned long long*)(pb + bws[i] + 4096) = cvt4(ru1v[i]);
    }
  };
  auto compute = [&](int b) {
    char* pb = (char*)sm[b];
    bf16x8 af[4], bg[2], bu[2];
    #pragma unroll
    for (int mi = 0; mi < 4; mi++)
      af[mi] = *(const bf16x8*)(pb + (wm * 4 + mi) * 1024 + l * 16);
    #pragma unroll
    for (int ni = 0; ni < 2; ni++) {
      bg[ni] = *(const bf16x8*)(pb + 8192  + (wn * 2 + ni) * 1024 + l * 16);
      bu[ni] = *(const bf16x8*)(pb + 12288 + (wn * 2 + ni) * 1024 + l * 16);
    }
    __builtin_amdgcn_s_setprio(1);
    #pragma unroll
    for (int mi = 0; mi < 4; mi++)
      #pragma unroll
      for (int ni = 0; ni < 2; ni++) {
        accg[mi][ni] = __builtin_amdgcn_mfma_f32_16x16x32_bf16(af[mi], bg[ni], accg[mi][ni], 0, 0, 0);
        accu[mi][ni] = __builtin_amdgcn_mfma_f32_16x16x32_bf16(af[mi], bu[ni], accu[mi][ni], 0, 0, 0);
      }
    __builtin_amdgcn_s_setprio(0);
  };

  loadS0(0); loadS1(1);
  writeS0(0);
  asm volatile("s_waitcnt lgkmcnt(0)" ::: "memory");
  __builtin_amdgcn_s_barrier();
  for (int kk = 0; kk < KC; kk += 2) {
    if (kk + 2 < KC) loadS0(kk + 2);
    compute(0);
    writeS1(1);
    asm volatile("s_waitcnt lgkmcnt(0)" ::: "memory");
    __builtin_amdgcn_s_barrier();
    if (kk + 3 < KC) loadS1(kk + 3);
    compute(1);
    if (kk + 2 < KC) writeS0(0);
    asm volatile("s_waitcnt lgkmcnt(0)" ::: "memory");
    __builtin_amdgcn_s_barrier();
  }

  // epilogue: silu(g)*u -> per-wave bounce (64 rows x 32 cols, stride 40) -> FM
  ushort_t* bw = &sm[0][0] + w * (64 * 40);
  #pragma unroll
  for (int mi = 0; mi < 4; mi++)
    #pragma unroll
    for (int ni = 0; ni < 2; ni++)
      #pragma unroll
      for (int j = 0; j < 4; j++) {
        float gg = accg[mi][ni][j], uu = accu[mi][ni][j];
        float s = (gg / (1.f + expf(-gg))) * uu;
        bw[(mi * 16 + g * 4 + j) * 40 + ni * 16 + fr] = f2bf(s);
      }
  #pragma unroll
  for (int rgi = 0; rgi < 4; rgi++) {
    bf16x8 v = *(const bf16x8*)&bw[(rgi * 16 + (l & 15)) * 40 + (l >> 4) * 8];
    OP[((size_t)(rg0 + wm * 4 + rgi) * KCd + kkd0) * 64 + l] = v;
  }
}

// ---------------- 5) down GEMM: fused fp32->bf16, LOW-REG, BK=64 -------------
// Tile 64 rows x 128 cols, 4 waves (each 64 rows x 32 cols), BK=64.
// acc[4][2] = 32 VGPR. LDS 2 x {A 8K, B 16K} = 48KB.
__global__ __launch_bounds__(256, 2) void down12_kernel(
    const ushort_t* __restrict__ interF, const ushort_t* __restrict__ interS,
    const float* __restrict__ wd_all, const float* __restrict__ swd,
    float* __restrict__ Dr, float* __restrict__ Ds,
    const int* __restrict__ rg2e)
{
  int bid = blockIdx.x;
  int tid = threadIdx.x, w = tid >> 6, l = tid & 63;
  int fr = l & 15, g = l >> 4;

  const bf16x8* AF; const float* WD;
  float* DO;
  int rgA0, c0, nk2, KCa, row0;

  if (bid < 4 * NRT64) {
    int cb = bid & 3, rt = bid >> 2;
    int e = rg2e[rt]; if (e < 0) return;
    AF = (const bf16x8*)interF;
    WD = wd_all + (size_t)e * H_DIM * I_DIM;
    rgA0 = rt * 4; c0 = cb * 128;
    KCa = I_DIM >> 5; nk2 = I_DIM >> 6;   // 64 chunks, 32 steps
    row0 = rt * 64;
    DO = Dr;
  } else {
    int b2 = bid - 4 * NRT64;
    int cb = b2 & 3, rt = b2 >> 2;
    AF = (const bf16x8*)interS;
    WD = swd;
    rgA0 = rt * 4; c0 = cb * 128;
    KCa = IS_DIM >> 5; nk2 = IS_DIM >> 6; // 32 chunks, 16 steps
    row0 = rt * 64;
    DO = Ds;
  }
  int Kd = KCa * 32;   // row length in floats

  // plane layout per buf (bytes): A [0,8192) (4 rg x 2 kc), B [8192,24576)
  __shared__ ushort_t sm[2][12288];   // 48 KB

  // A staging: 2 x 16B per thread (512 units: chunk = rg_a*2+kc)
  const bf16x8* abase[2]; int au[2];
  #pragma unroll
  for (int j = 0; j < 2; j++) {
    int u = tid + j * 256;
    au[j] = u;
    int ch = u >> 6;
    abase[j] = AF + ((size_t)(rgA0 + (ch >> 1)) * KCa + (ch & 1)) * 64 + (u & 63);
  }
  // B staging: 8 float4 per thread (128 rows x 16 float4 per 64-float step)
  const float* bsrc8[8]; int bws8[8];
  #pragma unroll
  for (int i = 0; i < 8; i++) {
    int f = tid + i * 256;           // 0..2047
    int row = f >> 4, q = f & 15;
    bsrc8[i] = WD + (size_t)(c0 + row) * Kd + q * 4;
    bws8[i] = 8192 + ((row >> 4) * 2 + (q >> 3)) * 1024
            + ((row & 15) + ((q & 7) >> 1) * 16) * 16 + (q & 1) * 8;
  }

  f32x4 acc[4][2] = {};
  bf16x8 ra0[2], ra1[2];
  float4 rb0[8], rb1[8];

  auto loadS0 = [&](int k2) {
    #pragma unroll
    for (int j = 0; j < 2; j++) ra0[j] = abase[j][(size_t)k2 * 128];
    #pragma unroll
    for (int i = 0; i < 8; i++) rb0[i] = *(const float4*)(bsrc8[i] + k2 * 64);
  };
  auto loadS1 = [&](int k2) {
    #pragma unroll
    for (int j = 0; j < 2; j++) ra1[j] = abase[j][(size_t)k2 * 128];
    #pragma unroll
    for (int i = 0; i < 8; i++) rb1[i] = *(const float4*)(bsrc8[i] + k2 * 64);
  };
  auto writeS0 = [&](int b) {
    bf16x8* ap = (bf16x8*)sm[b];
    ap[au[0]] = ra0[0]; ap[au[1]] = ra0[1];
    char* pb = (char*)sm[b];
    #pragma unroll
    for (int i = 0; i < 8; i++)
      *(unsigned long long*)(pb + bws8[i]) = cvt4(rb0[i]);
  };
  auto writeS1 = [&](int b) {
    bf16x8* ap = (bf16x8*)sm[b];
    ap[au[0]] = ra1[0]; ap[au[1]] = ra1[1];
    char* pb = (char*)sm[b];
    #pragma unroll
    for (int i = 0; i < 8; i++)
      *(unsigned long long*)(pb + bws8[i]) = cvt4(rb1[i]);
  };
  auto compute = [&](int b) {
    char* pb = (char*)sm[b];
    __builtin_amdgcn_s_setprio(1);
    #pragma unroll
    for (int s = 0; s < 2; s++) {
      bf16x8 af[4], bf[2];
      #pragma unroll
      for (int mi = 0; mi < 4; mi++)
        af[mi] = *(const bf16x8*)(pb + (mi * 2 + s) * 1024 + l * 16);
      #pragma unroll
      for (int ni = 0; ni < 2; ni++)
        bf[ni] = *(const bf16x8*)(pb + 8192 + ((w * 2 + ni) * 2 + s) * 1024 + l * 16);
      #pragma unroll
      for (int mi = 0; mi < 4; mi++)
        #pragma unroll
        for (int ni = 0; ni < 2; ni++)
          acc[mi][ni] = __builtin_amdgcn_mfma_f32_16x16x32_bf16(af[mi], bf[ni], acc[mi][ni], 0, 0, 0);
    }
    __builtin_amdgcn_s_setprio(0);
  };

  loadS0(0); loadS1(1);
  writeS0(0);
  asm volatile("s_waitcnt lgkmcnt(0)" ::: "memory");
  __builtin_amdgcn_s_barrier();
  for (int k2 = 0; k2 < nk2; k2 += 2) {
    if (k2 + 2 < nk2) loadS0(k2 + 2);
    compute(0);
    writeS1(1);
    asm volatile("s_waitcnt lgkmcnt(0)" ::: "memory");
    __builtin_amdgcn_s_barrier();
    if (k2 + 3 < nk2) loadS1(k2 + 3);
    compute(1);
    if (k2 + 2 < nk2) writeS0(0);
    asm volatile("s_waitcnt lgkmcnt(0)" ::: "memory");
    __builtin_amdgcn_s_barrier();
  }

  #pragma unroll
  for (int mi = 0; mi < 4; mi++)
    #pragma unroll
    for (int ni = 0; ni < 2; ni++)
      #pragma unroll
      for (int j = 0; j < 4; j++)
        DO[(size_t)(row0 + mi * 16 + g * 4 + j) * H_DIM + c0 + w * 32 + ni * 16 + fr]
            = acc[mi][ni][j];
}

// ---------------- 6) combine: out[t] = w0*Dr[r0] + w1*Dr[r1] + Ds[t] ----------
__global__ __launch_bounds__(128) void combine_kernel(
    const float* __restrict__ Dr, const float* __restrict__ Ds,
    const int* __restrict__ trow, const float* __restrict__ topk_w,
    float* __restrict__ out)
{
  int t = blockIdx.x, c = threadIdx.x;
  int r0 = trow[t * 2], r1 = trow[t * 2 + 1];
  float w0 = topk_w[t * 2], w1 = topk_w[t * 2 + 1];
  float4 a = ((const float4*)(Dr + (size_t)r0 * H_DIM))[c];
  float4 b = ((const float4*)(Dr + (size_t)r1 * H_DIM))[c];
  float4 s = ((const float4*)(Ds + (size_t)t * H_DIM))[c];
  float4 r;
  r.x = w0 * a.x + w1 * b.x + s.x;
  r.y = w0 * a.y + w1 * b.y + s.y;
  r.z = w0 * a.z + w1 * b.z + s.z;
  r.w = w0 * a.w + w1 * b.w + s.w;
  ((float4*)(out + (size_t)t * H_DIM))[c] = r;
}

// ---------------- launch ----------------
extern "C" void kernel_launch(void* const* d_in, const int* in_sizes, int n_in,
                              void* d_out, int out_size, void* d_ws, size_t ws_size,
                              hipStream_t stream) {
  const float* x       = (const float*)d_in[0];
  const float* gate_w  = (const float*)d_in[1];
  const float* w_gate  = (const float*)d_in[2];
  const float* w_up    = (const float*)d_in[3];
  const float* w_down  = (const float*)d_in[4];
  const float* sw_gate = (const float*)d_in[5];
  const float* sw_up   = (const float*)d_in[6];
  const float* sw_down = (const float*)d_in[7];
  float* out = (float*)d_out;

  char* ws = (char*)d_ws;
  int*   counts    = (int*)ws;                      // 16
  int*   cursor    = (int*)(ws + 64);               // 16
  int*   offp      = (int*)(ws + 128);              // 17
  int*   rt2e      = (int*)(ws + 256);              // 48
  int*   rg2e      = (int*)(ws + 448);              // 96
  int*   topk_idx  = (int*)(ws + 832);              // 4096
  float* topk_w    = (float*)(ws + 17216);          // 4096
  int*   trow      = (int*)(ws + 33600);            // 4096
  int*   row_token = (int*)(ws + 49984);            // RPMAX
  size_t off = 49984 + (size_t)RPMAX * 4;
  off = (off + 255) & ~(size_t)255;
  float*    logits = (float*)(ws + off);    off += (size_t)T_TOK * E_NUM * 4;       // 128 KiB
  ushort_t* xgf  = (ushort_t*)(ws + off); off += (size_t)RPMAX * H_DIM * 2;         // 6 MiB
  ushort_t* xsf  = (ushort_t*)(ws + off); off += (size_t)T_TOK * H_DIM * 2;         // 2 MiB
  ushort_t* interF = (ushort_t*)(ws + off); off += (size_t)RPMAX * I_DIM * 2;       // 24 MiB
  ushort_t* interS = (ushort_t*)(ws + off); off += (size_t)T_TOK * IS_DIM * 2;      // 4 MiB
  float*    Dr     = (float*)(ws + off);    off += (size_t)RPMAX * H_DIM * 4;       // 12 MiB
  float*    Ds     = (float*)(ws + off);    off += (size_t)T_TOK * H_DIM * 4;       // 4 MiB

  hipMemsetAsync(counts, 0, 64, stream);
  logits_kernel<<<T_TOK / 16, 256, 0, stream>>>(x, gate_w, logits);
  topk_kernel<<<T_TOK / 256, 256, 0, stream>>>(logits, topk_idx, topk_w, counts);
  offsets_kernel<<<1, 128, 0, stream>>>(counts, offp, cursor, rt2e, rg2e);
  initrows_kernel<<<RPMAX / 256, 256, 0, stream>>>(row_token);
  scatter_kernel<<<(T_TOK + 255) / 256, 256, 0, stream>>>(topk_idx, topk_w, offp, cursor,
                                                          row_token, trow);
  // A-operands into FM bf16
  gatherA_kernel<4><<<RPMAX * H_DIM / 8 / 256, 256, 0, stream>>>(
      x, row_token, xgf, RPMAX * H_DIM / 8, H_DIM);
  gatherA_kernel<4><<<T_TOK * H_DIM / 8 / 256, 256, 0, stream>>>(
      x, nullptr, xsf, T_TOK * H_DIM / 8, H_DIM);

  // GU (fused conversion): routed 32 cb x 48 rt = 1536 + shared 16 x 16 = 256
  gu12_kernel<<<32 * NRT128 + 16 * 16, 256, 0, stream>>>(
      xgf, xsf, w_gate, w_up, sw_gate, sw_up, interF, interS, rt2e);
  // down (fused conversion): routed 4 cb x 96 rt = 384 + shared 4 x 32 = 128
  down12_kernel<<<4 * NRT64 + 4 * 32, 256, 0, stream>>>(
      interF, interS, w_down, sw_down, Dr, Ds, rg2e);
  // combine
  combine_kernel<<<T_TOK, 128, 0, stream>>>(Dr, Ds, trow, topk_w, out);
}